// Round 6
// baseline (256.823 us; speedup 1.0000x reference)
//
#include <hip/hip_runtime.h>
#include <math.h>

namespace {

constexpr int NROW = 32768;   // BS*A rows
constexpr int HDIM = 64;
constexpr int DH   = 512;     // latent half-dim

typedef __attribute__((ext_vector_type(8))) short bf16x8;
typedef __attribute__((ext_vector_type(4))) float f32x4;
typedef __attribute__((ext_vector_type(4))) unsigned uint4e;
typedef __attribute__((ext_vector_type(2))) unsigned uint2e;

__device__ __forceinline__ float sigmoidf_(float x) { return 1.f / (1.f + __expf(-x)); }
__device__ __forceinline__ float lrelu_(float x) { return x > 0.f ? x : 0.01f * x; }
// fast pack: round-half-up bf16 pair (a -> low16, b -> high16)
__device__ __forceinline__ unsigned pkbf(float a, float b) {
  unsigned ua = __float_as_uint(a) + 0x8000u;
  unsigned ub = __float_as_uint(b) + 0x8000u;
  return __builtin_amdgcn_perm(ub, ua, 0x07060302);
}

// K1+K2 fused: 512 threads, 8 waves x 16 rows; staging loads batched (unrolled).
__global__ __launch_bounds__(512, 1) void k_fgru(
    const float* __restrict__ in,      // [N][96]
    const float* __restrict__ hprev,   // [N][64]
    const float* __restrict__ fc1w, const float* __restrict__ fc1b,
    const float* __restrict__ wih, const float* __restrict__ whh,
    const float* __restrict__ bih, const float* __restrict__ bhh,
    float* __restrict__ hT, float* __restrict__ hout) {
  __shared__ char smem[73728];
  const int t = threadIdx.x;
  const int n0 = blockIdx.x * 128;
  short*    xS = (short*)smem;                 // [128][72] shorts
  unsigned* gU = (unsigned*)(smem + 18432);    // [6][64][36]
  float*    trF = (float*)(smem + 18432);      // [64][133] f32, overlays gU after GRU

  const float2* wih2 = (const float2*)wih;
  const float2* whh2 = (const float2*)whh;
  {  // gate weight staging: batched loads, then packs
    float2 wv[12];
#pragma unroll
    for (int i = 0; i < 12; ++i) {
      int idx = t + 512 * i;
      int row = idx >> 5, kp = idx & 31;
      wv[i] = wih2[row * 32 + kp];
    }
#pragma unroll
    for (int i = 0; i < 12; ++i) {
      int idx = t + 512 * i;
      int row = idx >> 5, kp = idx & 31;
      int gate = row >> 6, cl = row & 63;
      gU[(gate * 64 + cl) * 36 + kp] = pkbf(wv[i].x, wv[i].y);
    }
#pragma unroll
    for (int i = 0; i < 12; ++i) {
      int idx = t + 512 * i;
      int row = idx >> 5, kp = idx & 31;
      wv[i] = whh2[row * 32 + kp];
    }
#pragma unroll
    for (int i = 0; i < 12; ++i) {
      int idx = t + 512 * i;
      int row = idx >> 5, kp = idx & 31;
      int gate = row >> 6, cl = row & 63;
      gU[((gate + 3) * 64 + cl) * 36 + kp] = pkbf(wv[i].x, wv[i].y);
    }
  }

  const int w = t >> 6, l = t & 63;
  const int m = l & 15, g = l >> 4;
  const int rowA = n0 + w * 16 + m;      // A-operand row for this lane

  // ---- fc1 phase ----
  bf16x8 af[3];
#pragma unroll
  for (int ks = 0; ks < 3; ++ks) {
    const float4* p = (const float4*)(in + (size_t)rowA * 96 + ks * 32 + g * 8);
    float4 a = p[0], b = p[1];
    union { unsigned u[4]; bf16x8 h; } tw;
    tw.u[0] = pkbf(a.x, a.y); tw.u[1] = pkbf(a.z, a.w);
    tw.u[2] = pkbf(b.x, b.y); tw.u[3] = pkbf(b.z, b.w);
    af[ks] = tw.h;
  }
  {
    f32x4 accx[4];
#pragma unroll
    for (int ct = 0; ct < 4; ++ct) accx[ct] = (f32x4){0.f, 0.f, 0.f, 0.f};
#pragma unroll
    for (int ct = 0; ct < 4; ++ct)
#pragma unroll
      for (int ks = 0; ks < 3; ++ks) {
        const float4* p = (const float4*)(fc1w + (ct * 16 + m) * 96 + ks * 32 + g * 8);
        float4 a = p[0], b = p[1];
        union { unsigned u[4]; bf16x8 h; } tw;
        tw.u[0] = pkbf(a.x, a.y); tw.u[1] = pkbf(a.z, a.w);
        tw.u[2] = pkbf(b.x, b.y); tw.u[3] = pkbf(b.z, b.w);
        accx[ct] = __builtin_amdgcn_mfma_f32_16x16x32_bf16(af[ks], tw.h, accx[ct], 0, 0, 0);
      }
#pragma unroll
    for (int ct = 0; ct < 4; ++ct) {
      int c = ct * 16 + m;
      float bc = fc1b[c];
#pragma unroll
      for (int reg = 0; reg < 4; ++reg) {
        int nl = w * 16 + g * 4 + reg;
        float v = fmaxf(accx[ct][reg] + bc, 0.f);
        xS[nl * 72 + c] = (short)((__float_as_uint(v) + 0x8000u) >> 16);
      }
    }
  }
  __syncthreads();   // xS ready + gU ready

  // ---- GRU phase ----
  bf16x8 ax[2], ah[2];
#pragma unroll
  for (int ks = 0; ks < 2; ++ks) {
    ax[ks] = *(const bf16x8*)(xS + (w * 16 + m) * 72 + ks * 32 + g * 8);
    const float4* p = (const float4*)(hprev + (size_t)rowA * 64 + ks * 32 + g * 8);
    float4 a = p[0], b = p[1];
    union { unsigned u[4]; bf16x8 h; } tw;
    tw.u[0] = pkbf(a.x, a.y); tw.u[1] = pkbf(a.z, a.w);
    tw.u[2] = pkbf(b.x, b.y); tw.u[3] = pkbf(b.z, b.w);
    ah[ks] = tw.h;
  }
  const short* gS = (const short*)gU;
  float hc[4][4];
#pragma unroll 1
  for (int ct = 0; ct < 4; ++ct) {
    f32x4 a_ir = (f32x4){0.f,0.f,0.f,0.f}, a_iz = (f32x4){0.f,0.f,0.f,0.f},
          a_in = (f32x4){0.f,0.f,0.f,0.f}, a_hr = (f32x4){0.f,0.f,0.f,0.f},
          a_hz = (f32x4){0.f,0.f,0.f,0.f}, a_hn = (f32x4){0.f,0.f,0.f,0.f};
    int crow = ct * 16 + m;
#pragma unroll
    for (int ks = 0; ks < 2; ++ks) {
      bf16x8 b0 = *(const bf16x8*)(gS + (0 * 64 + crow) * 72 + ks * 32 + g * 8);
      bf16x8 b1 = *(const bf16x8*)(gS + (1 * 64 + crow) * 72 + ks * 32 + g * 8);
      bf16x8 b2 = *(const bf16x8*)(gS + (2 * 64 + crow) * 72 + ks * 32 + g * 8);
      bf16x8 b3 = *(const bf16x8*)(gS + (3 * 64 + crow) * 72 + ks * 32 + g * 8);
      bf16x8 b4 = *(const bf16x8*)(gS + (4 * 64 + crow) * 72 + ks * 32 + g * 8);
      bf16x8 b5 = *(const bf16x8*)(gS + (5 * 64 + crow) * 72 + ks * 32 + g * 8);
      a_ir = __builtin_amdgcn_mfma_f32_16x16x32_bf16(ax[ks], b0, a_ir, 0, 0, 0);
      a_iz = __builtin_amdgcn_mfma_f32_16x16x32_bf16(ax[ks], b1, a_iz, 0, 0, 0);
      a_in = __builtin_amdgcn_mfma_f32_16x16x32_bf16(ax[ks], b2, a_in, 0, 0, 0);
      a_hr = __builtin_amdgcn_mfma_f32_16x16x32_bf16(ah[ks], b3, a_hr, 0, 0, 0);
      a_hz = __builtin_amdgcn_mfma_f32_16x16x32_bf16(ah[ks], b4, a_hz, 0, 0, 0);
      a_hn = __builtin_amdgcn_mfma_f32_16x16x32_bf16(ah[ks], b5, a_hn, 0, 0, 0);
    }
    float bir = bih[crow], biz = bih[64 + crow], bin = bih[128 + crow];
    float bhr = bhh[crow], bhz = bhh[64 + crow], bhn = bhh[128 + crow];
#pragma unroll
    for (int reg = 0; reg < 4; ++reg) {
      int nl = w * 16 + g * 4 + reg;
      float hv = hprev[(size_t)(n0 + nl) * 64 + crow];
      float r  = sigmoidf_(a_ir[reg] + bir + a_hr[reg] + bhr);
      float z  = sigmoidf_(a_iz[reg] + biz + a_hz[reg] + bhz);
      float nn = tanhf(a_in[reg] + bin + r * (a_hn[reg] + bhn));
      hc[ct][reg] = (1.f - z) * nn + z * hv;
    }
  }
  __syncthreads();   // all waves done reading gU before trF overlay
#pragma unroll
  for (int ct = 0; ct < 4; ++ct)
#pragma unroll
    for (int reg = 0; reg < 4; ++reg)
      trF[(ct * 16 + m) * 133 + w * 16 + g * 4 + reg] = hc[ct][reg];
  __syncthreads();
#pragma unroll
  for (int i = 0; i < 16; ++i) {
    int idx = t + 512 * i;
    int nl = idx & 127, cl = idx >> 7;
    hT[(size_t)cl * NROW + n0 + nl] = trF[cl * 133 + nl];
  }
#pragma unroll
  for (int i = 0; i < 16; ++i) {
    int idx = t + 512 * i;
    int c = idx & 63, nl = idx >> 6;
    hout[(size_t)(n0 + nl) * 64 + c] = trF[c * 133 + nl];
  }
}

// K3 (MFMA): 96-channel fused head GEMM (fc2 16 + qk 16 + ew1 64), K=64.
// Staging de-serialized: batched h loads; copy-rows pass + dedicated qk pass.
__global__ __launch_bounds__(256) void k_heads(const float* __restrict__ hT,
    const float* __restrict__ fc2w, const float* __restrict__ fc2b,
    const float* __restrict__ wqw, const float* __restrict__ wkw,
    const float* __restrict__ ew1, const float* __restrict__ eb1,
    float* __restrict__ qT, float* __restrict__ qkT, float* __restrict__ z1T,
    float* __restrict__ part) {
  __shared__ char smem[36864];
  const int t = threadIdx.x;
  const int n0 = blockIdx.x * 128;
  unsigned* hU = (unsigned*)smem;                 // [128][36]
  unsigned* wU = (unsigned*)(smem + 18432);       // [96][36]
  float* sp1 = (float*)(smem + 18432 + 13824);    // [4][64]
  float* sp2 = sp1 + 256;                         // [4][64]
  const float qs = 0.17677669529663687f;          // 1/sqrt(32)

  {  // h staging: batched loads
    float va[16], vb[16];
#pragma unroll
    for (int i = 0; i < 16; ++i) {
      int idx = t + 256 * i;
      int nl = idx & 127, kp = idx >> 7;
      va[i] = hT[(size_t)(2 * kp) * NROW + n0 + nl];
      vb[i] = hT[(size_t)(2 * kp + 1) * NROW + n0 + nl];
    }
#pragma unroll
    for (int i = 0; i < 16; ++i) {
      int idx = t + 256 * i;
      int nl = idx & 127, kp = idx >> 7;
      hU[nl * 36 + kp] = pkbf(va[i], vb[i]);
    }
  }
  {  // weight copies: fc2 (wU rows 0..15) + ew1 (wU rows 32..95)
    float2 wv[10];
#pragma unroll
    for (int i = 0; i < 10; ++i) {
      int idx = t + 256 * i;            // 0..2559
      int kp = idx & 31, cl = idx >> 5; // 0..79
      const float* src = (cl < 16) ? (fc2w + cl * 64) : (ew1 + (cl - 16) * 64);
      wv[i] = *(const float2*)(src + 2 * kp);
    }
#pragma unroll
    for (int i = 0; i < 10; ++i) {
      int idx = t + 256 * i;
      int kp = idx & 31, cl = idx >> 5;
      int dst = (cl < 16) ? cl : (cl + 16);
      wU[dst * 36 + kp] = pkbf(wv[i].x, wv[i].y);
    }
  }
  {  // qk rows (wU rows 16..31): qs * Wk^T Wq, inner loop unrolled
    int kp = t & 31, ll = t >> 5;   // ll 0..7; rows ll, ll+8
#pragma unroll
    for (int h = 0; h < 2; ++h) {
      int row = ll + 8 * h;
      float s0 = 0.f, s1 = 0.f;
#pragma unroll
      for (int a = 0; a < 32; ++a) {
        float wk = wkw[a * 16 + row];
        s0 = fmaf(wk, wqw[a * 64 + 2 * kp], s0);
        s1 = fmaf(wk, wqw[a * 64 + 2 * kp + 1], s1);
      }
      wU[(16 + row) * 36 + kp] = pkbf(s0 * qs, s1 * qs);
    }
  }
  __syncthreads();

  const int w = t >> 6, l = t & 63;
  const int m = l & 15, g = l >> 4;
  const short* sH = (const short*)hU;
  const short* sW = (const short*)wU;

  bf16x8 af[2][2];
#pragma unroll
  for (int mt = 0; mt < 2; ++mt)
#pragma unroll
    for (int ks = 0; ks < 2; ++ks)
      af[mt][ks] = *(const bf16x8*)(sH + (w * 32 + mt * 16 + m) * 72 + ks * 32 + g * 8);

  f32x4 acc[2][6];
#pragma unroll
  for (int mt = 0; mt < 2; ++mt)
#pragma unroll
    for (int ct = 0; ct < 6; ++ct) acc[mt][ct] = (f32x4){0.f, 0.f, 0.f, 0.f};
#pragma unroll
  for (int ct = 0; ct < 6; ++ct)
#pragma unroll
    for (int ks = 0; ks < 2; ++ks) {
      bf16x8 bw = *(const bf16x8*)(sW + (ct * 16 + m) * 72 + ks * 32 + g * 8);
#pragma unroll
      for (int mt = 0; mt < 2; ++mt)
        acc[mt][ct] = __builtin_amdgcn_mfma_f32_16x16x32_bf16(af[mt][ks], bw, acc[mt][ct], 0, 0, 0);
    }

  float s1[4], s2[4];
#pragma unroll
  for (int zt = 0; zt < 4; ++zt) { s1[zt] = 0.f; s2[zt] = 0.f; }
#pragma unroll
  for (int mt = 0; mt < 2; ++mt) {
    int nb = n0 + w * 32 + mt * 16 + g * 4;
    {  // q head: c = m
      float bc = fc2b[m];
      f32x4 v;
#pragma unroll
      for (int reg = 0; reg < 4; ++reg) v[reg] = acc[mt][0][reg] + bc;
      *(f32x4*)(qT + (size_t)m * NROW + nb) = v;
    }
    // qk head: l' = m, no bias
    *(f32x4*)(qkT + (size_t)m * NROW + nb) = acc[mt][1];
#pragma unroll
    for (int ct = 2; ct < 6; ++ct) {  // z1 head: z = (ct-2)*16 + m
      int z = (ct - 2) * 16 + m;
      float bc = eb1[z];
      f32x4 v;
#pragma unroll
      for (int reg = 0; reg < 4; ++reg) {
        float zv = acc[mt][ct][reg] + bc;
        v[reg] = zv;
        s1[ct - 2] += zv;
        s2[ct - 2] = fmaf(zv, zv, s2[ct - 2]);
      }
      *(f32x4*)(z1T + (size_t)z * NROW + nb) = v;
    }
  }
#pragma unroll
  for (int zt = 0; zt < 4; ++zt) {
    s1[zt] += __shfl_down(s1[zt], 16, 64);
    s1[zt] += __shfl_down(s1[zt], 32, 64);
    s2[zt] += __shfl_down(s2[zt], 16, 64);
    s2[zt] += __shfl_down(s2[zt], 32, 64);
  }
  if (l < 16) {
#pragma unroll
    for (int zt = 0; zt < 4; ++zt) {
      sp1[w * 64 + zt * 16 + m] = s1[zt];
      sp2[w * 64 + zt * 16 + m] = s2[zt];
    }
  }
  __syncthreads();
  if (t < 64) {
    float a1 = sp1[t] + sp1[64 + t] + sp1[128 + t] + sp1[192 + t];
    float a2 = sp2[t] + sp2[64 + t] + sp2[128 + t] + sp2[192 + t];
    part[(size_t)blockIdx.x * 128 + t] = a1;
    part[(size_t)blockIdx.x * 128 + 64 + t] = a2;
  }
}

// K4: finalize BN stats (256 threads, 4-way sliced)
__global__ __launch_bounds__(256) void k_bnstat(const float* __restrict__ part,
    const float* __restrict__ bng, const float* __restrict__ bnb,
    float* __restrict__ stat) {
  __shared__ float red[512];
  const int t = threadIdx.x;        // 256
  const int c = t & 63, q = t >> 6; // q 0..3
  float s1 = 0.f, s2 = 0.f;
#pragma unroll 4
  for (int b = q; b < 256; b += 4) {
    s1 += part[(size_t)b * 128 + c];
    s2 += part[(size_t)b * 128 + 64 + c];
  }
  red[q * 64 + c] = s1;
  red[256 + q * 64 + c] = s2;
  __syncthreads();
  if (t < 64) {
    float a1 = red[t] + red[64 + t] + red[128 + t] + red[192 + t];
    float a2 = red[256 + t] + red[320 + t] + red[384 + t] + red[448 + t];
    float mean = a1 * (1.f / NROW);
    float var = a2 * (1.f / NROW) - mean * mean;
    float rstd = rsqrtf(var + 1e-5f);
    float sc = bng[t] * rstd;
    stat[t] = sc;
    stat[64 + t] = bnb[t] - mean * sc;
  }
}

// K5 (v9b): 512 blocks x 512 threads; block = 128 rows x 256-col half (4 chunks).
// Triple-buffered W: per-chunk barrier sits AFTER the LDS pack and BEFORE new
// load issue -> the implicit vmcnt(0) drain at each barrier only waits on loads
// aged a full chunk. eps prefetch distance 2. W loads 4x dwordx4 (full 64x64).
__global__ __launch_bounds__(512, 4) void k_emb_gemm(const float* __restrict__ z1T,
    const float* __restrict__ stat,
    const float* __restrict__ ew2, const float* __restrict__ eb2,
    const float* __restrict__ eps,
    unsigned* __restrict__ latB16g) {
  __shared__ char smem[73728];   // A [128][36]u32 + 3x W buf [128][36]u32
  const int t = threadIdx.x;
  const int nb = blockIdx.x >> 1;
  const int half = blockIdx.x & 1;
  const int n0 = nb * 128;
  const int ch0 = half * 256;    // this block's 4 chunks: cols [ch0, ch0+256)

  unsigned* aU = (unsigned*)smem;
  unsigned* wB0 = (unsigned*)(smem + 18432);
  unsigned* wB1 = (unsigned*)(smem + 36864);
  unsigned* wB2 = (unsigned*)(smem + 55296);

  const int w = t >> 6, l = t & 63;
  const int m = l & 15, g = l >> 4;
  const float4* ew2_4 = (const float4*)ew2;
  const float stdfloor = 0.04472135955f;   // sqrt(0.002)
  const int rowG = n0 + w * 16 + g * 4;    // + reg = global row
  const int kp4 = t & 15, cl = t >> 4;     // W-staging: kp4 0..15 (float4 col), cl 0..31 (row)

  float4 wmA, wmB, wlA, wlB;               // in-flight W chunk (regs)
  float epsC[16], epsN[16], epsT[16];

  // W chunk c2 -> regs (4x dwordx4): mu rows cl, cl+32; lv rows cl, cl+32
  auto loadW = [&](int c2) {
    wmA = ew2_4[(size_t)(c2 + cl) * 16 + kp4];
    wmB = ew2_4[(size_t)(c2 + 32 + cl) * 16 + kp4];
    wlA = ew2_4[(size_t)(512 + c2 + cl) * 16 + kp4];
    wlB = ew2_4[(size_t)(512 + c2 + 32 + cl) * 16 + kp4];
  };
  // regs -> LDS buffer (4x ds_write_b64); rows 0..63 mu, 64..127 lv
  auto packW = [&](unsigned* bp) {
    *(uint2e*)(bp + cl * 36 + kp4 * 2) = (uint2e){pkbf(wmA.x, wmA.y), pkbf(wmA.z, wmA.w)};
    *(uint2e*)(bp + (32 + cl) * 36 + kp4 * 2) = (uint2e){pkbf(wmB.x, wmB.y), pkbf(wmB.z, wmB.w)};
    *(uint2e*)(bp + (64 + cl) * 36 + kp4 * 2) = (uint2e){pkbf(wlA.x, wlA.y), pkbf(wlA.z, wlA.w)};
    *(uint2e*)(bp + (96 + cl) * 36 + kp4 * 2) = (uint2e){pkbf(wlB.x, wlB.y), pkbf(wlB.z, wlB.w)};
  };
  auto loadE = [&](int c0v, float* arr) {
#pragma unroll
    for (int ct = 0; ct < 4; ++ct)
#pragma unroll
      for (int reg = 0; reg < 4; ++reg)
        arr[ct * 4 + reg] = eps[(size_t)(rowG + reg) * 512 + c0v + ct * 16 + m];
  };

  // ---- A staging: z1T -> BN -> lrelu -> bf16 pack ----
  {
    float va[8], vb[8];
#pragma unroll
    for (int i = 0; i < 8; ++i) {
      int idx = t + 512 * i;               // 0..4095
      int nl = idx & 127, kp = idx >> 7;   // kp 0..31
      va[i] = z1T[(size_t)(2 * kp) * NROW + n0 + nl];
      vb[i] = z1T[(size_t)(2 * kp + 1) * NROW + n0 + nl];
    }
#pragma unroll
    for (int i = 0; i < 8; ++i) {
      int idx = t + 512 * i;
      int nl = idx & 127, kp = idx >> 7;
      float v0 = lrelu_(fmaf(stat[2 * kp], va[i], stat[64 + 2 * kp]));
      float v1 = lrelu_(fmaf(stat[2 * kp + 1], vb[i], stat[64 + 2 * kp + 1]));
      aU[nl * 36 + kp] = pkbf(v0, v1);
    }
  }
  // W[0] -> buf0; W[1] -> regs; eps[0],eps[1] -> regs
  loadW(ch0);
  packW(wB0);
  loadW(ch0 + 64);
  loadE(ch0, epsC);
  loadE(ch0 + 64, epsN);
  __syncthreads();   // A + buf0 visible (drains prologue loads once)

  // A fragments: constant across chunks
  const short* sA = (const short*)aU;
  bf16x8 af[2];
#pragma unroll
  for (int ks = 0; ks < 2; ++ks)
    af[ks] = *(const bf16x8*)(sA + (w * 16 + m) * 72 + ks * 32 + g * 8);

  // chunk compute: MFMA from wb, epilogue with epsArr, columns c0..c0+63
  auto compute = [&](const unsigned* wbu, int c0, const float* epsArr) {
    const short* sW = (const short*)wbu;
    f32x4 accm[4], accl[4];
#pragma unroll
    for (int ct = 0; ct < 4; ++ct) {
      accm[ct] = (f32x4){0.f, 0.f, 0.f, 0.f};
      accl[ct] = (f32x4){0.f, 0.f, 0.f, 0.f};
    }
#pragma unroll
    for (int ct = 0; ct < 4; ++ct)
#pragma unroll
      for (int ks = 0; ks < 2; ++ks) {
        bf16x8 bm = *(const bf16x8*)(sW + (ct * 16 + m) * 72 + ks * 32 + g * 8);
        bf16x8 bl = *(const bf16x8*)(sW + (64 + ct * 16 + m) * 72 + ks * 32 + g * 8);
        accm[ct] = __builtin_amdgcn_mfma_f32_16x16x32_bf16(af[ks], bm, accm[ct], 0, 0, 0);
        accl[ct] = __builtin_amdgcn_mfma_f32_16x16x32_bf16(af[ks], bl, accl[ct], 0, 0, 0);
      }
#pragma unroll
    for (int ct = 0; ct < 4; ++ct) {
      int c = c0 + ct * 16 + m;
      float ebm = eb2[c], ebl = eb2[DH + c];
#pragma unroll
      for (int reg = 0; reg < 4; ++reg) {
        float mu = accm[ct][reg] + ebm;
        float lv = accl[ct][reg] + ebl;
        float sd = fmaxf(__expf(0.5f * lv), stdfloor);
        float lat = fmaf(sd, epsArr[ct * 4 + reg], mu);
        float lat2 = __shfl_xor(lat, 1, 64);
        if (!(m & 1)) {
          latB16g[(size_t)(rowG + reg) * 256 + (c0 >> 1) + ct * 8 + (m >> 1)] =
              pkbf(lat, lat2);
        }
      }
    }
  };

  // ---- chunk 0 ----
  packW(wB1);                       // W[1] regs -> buf1
  __syncthreads();                  // drain waits only prologue-aged loads
  loadW(ch0 + 128);                 // issue W[2]
  loadE(ch0 + 128, epsT);           // issue eps[2]
  compute(wB0, ch0, epsC);
#pragma unroll
  for (int i = 0; i < 16; ++i) { epsC[i] = epsN[i]; epsN[i] = epsT[i]; }
  // ---- chunk 1 ----
  packW(wB2);                       // W[2] (aged one chunk)
  __syncthreads();
  loadW(ch0 + 192);                 // issue W[3]
  loadE(ch0 + 192, epsT);           // issue eps[3]
  compute(wB1, ch0 + 64, epsC);
#pragma unroll
  for (int i = 0; i < 16; ++i) { epsC[i] = epsN[i]; epsN[i] = epsT[i]; }
  // ---- chunk 2 ----
  packW(wB0);                       // W[3] (aged one chunk)
  __syncthreads();
  compute(wB2, ch0 + 128, epsC);
#pragma unroll
  for (int i = 0; i < 16; ++i) epsC[i] = epsN[i];
  // ---- chunk 3 ---- (buf0 packed before chunk-2 barrier; no new barrier needed)
  compute(wB0, ch0 + 192, epsC);
}

// K7 (MFMA): one block per b. Logit+softmax in-kernel from bf16 latent.
constexpr int LATB_OFF = 0;        // [1024][20] bf16, 40B rows (r = i*32+j)
constexpr int H3B_OFF  = 40960;    // [32][72] bf16, 144B rows
constexpr int W1H_OFF  = 45568;    // [64][72] bf16
constexpr int W1L_OFF  = 54784;    // [64][20] bf16
constexpr int W2P_OFF  = 57344;    // [16][72] bf16 (pi-permuted c)
constexpr int ALL_OFF  = 59648;    // [32][33] f32 alpha
constexpr int MT_OFF   = 63872;    // 4 waves x 2560B private transpose buf
constexpr int QKL_OFF  = 74112;    // [32][20] f32 qk
__global__ __launch_bounds__(256, 1) void k_msg(
    const unsigned* __restrict__ latB16g, const float* __restrict__ qkT,
    const float* __restrict__ qT, const float* __restrict__ hrow,
    const float* __restrict__ w1, const float* __restrict__ b1,
    const float* __restrict__ w2, const float* __restrict__ b2,
    float* __restrict__ out) {
  __shared__ char smem[76672];
  const int t = threadIdx.x;
  const int b = blockIdx.x;
  const int b32 = b * 32;
  unsigned* latB_dw = (unsigned*)(smem + LATB_OFF);

  // ---- staging (batched loads per scope) ----
  {  // latB: bf16 copy, 2 batches of 4 x 16B
    const uint4e* g4 = (const uint4e*)latB16g + (size_t)b32 * 64;
#pragma unroll
    for (int half = 0; half < 2; ++half) {
      uint4e v[4];
#pragma unroll
      for (int it = 0; it < 4; ++it) v[it] = g4[t + 256 * (4 * half + it)];
#pragma unroll
      for (int it = 0; it < 4; ++it) {
        int idx = t + 256 * (4 * half + it);
        int i = idx >> 6;
        int rem = idx & 63;
        int j = rem >> 1, hh = rem & 1;
        unsigned* dst = latB_dw + (i * 32 + j) * 10 + hh * 4;
        *(uint2e*)dst = (uint2e){v[it].x, v[it].y};
        *(uint2e*)(dst + 2) = (uint2e){v[it].z, v[it].w};
      }
    }
  }
  {  // qkL[i][l] from qkT
    float* qkL = (float*)(smem + QKL_OFF);
    int i = t & 31;
    float v0 = qkT[(size_t)((t >> 5)) * NROW + b32 + i];
    float v1 = qkT[(size_t)((t >> 5) + 8) * NROW + b32 + i];
    qkL[i * 20 + (t >> 5)] = v0;
    qkL[i * 20 + (t >> 5) + 8] = v1;
  }
  {  // h3B[j][k] bf16 from row-major h
    int cp = t & 31, jj = t >> 5;
    const float2* h2 = (const float2*)hrow;
    float2 hv[4];
#pragma unroll
    for (int it = 0; it < 4; ++it)
      hv[it] = h2[((size_t)(b32 + jj + 8 * it) * 64 + 2 * cp) >> 1];
    unsigned* dst = (unsigned*)(smem + H3B_OFF);
#pragma unroll
    for (int it = 0; it < 4; ++it)
      dst[(jj + 8 * it) * 36 + cp] = pkbf(hv[it].x, hv[it].y);
  }
  {  // w1hL[c][k] (k<64)
    int kp = t & 31, cc = t >> 5;
    const float2* w12 = (const float2*)w1;
    float2 wv[8];
#pragma unroll
    for (int it = 0; it < 8; ++it)
      wv[it] = w12[((cc + 8 * it) * 80 + 2 * kp) >> 1];
    unsigned* dst = (unsigned*)(smem + W1H_OFF);
#pragma unroll
    for (int it = 0; it < 8; ++it)
      dst[(cc + 8 * it) * 36 + kp] = pkbf(wv[it].x, wv[it].y);
  }
  {  // w1latL[c][l]
    int lp = t & 7, cc = t >> 3;
    const float2* w12 = (const float2*)w1;
    float2 wv[2];
#pragma unroll
    for (int it = 0; it < 2; ++it)
      wv[it] = w12[((cc + 32 * it) * 80 + 64 + 2 * lp) >> 1];
    unsigned* dst = (unsigned*)(smem + W1L_OFF);
#pragma unroll
    for (int it = 0; it < 2; ++it)
      dst[(cc + 32 * it) * 10 + lp] = pkbf(wv[it].x, wv[it].y);
  }
  {  // w2P[nn][p] = w2[nn][c(p)], c(p) = ((p>>2)&3)*16 + (p>>4)*4 + (p&3)
    int pp = t & 31, nn = t >> 5;
    const float2* w22 = (const float2*)w2;
    int p = 2 * pp;
    int c = ((p >> 2) & 3) * 16 + (p >> 4) * 4 + (p & 3);
    float2 wv0 = w22[(nn * 64 + c) >> 1];
    float2 wv1 = w22[((nn + 8) * 64 + c) >> 1];
    unsigned* dst = (unsigned*)(smem + W2P_OFF);
    dst[nn * 36 + pp] = pkbf(wv0.x, wv0.y);
    dst[(nn + 8) * 36 + pp] = pkbf(wv1.x, wv1.y);
  }
  __syncthreads();

  // ---- logits + softmax -> alL (reads latB + qkL) ----
  {
    const float* qkL = (const float*)(smem + QKL_OFF);
    float* alL = (float*)(smem + ALL_OFF);
#pragma unroll 1
    for (int p = 0; p < 4; ++p) {
      int i = (t >> 5) + 8 * p;
      int j = t & 31;
      const unsigned* lr = latB_dw + (i * 32 + j) * 10;
      float acc = 0.f;
#pragma unroll
      for (int d = 0; d < 8; ++d) {
        unsigned u = lr[d];
        float lo = __uint_as_float(u << 16);
        float hi = __uint_as_float(u & 0xffff0000u);
        acc = fmaf(lo, qkL[i * 20 + 2 * d], acc);
        acc = fmaf(hi, qkL[i * 20 + 2 * d + 1], acc);
      }
      if (j == i) acc = -1e9f;
      float mx = acc;
#pragma unroll
      for (int msk = 16; msk > 0; msk >>= 1) mx = fmaxf(mx, __shfl_xor(mx, msk, 32));
      float e = __expf(acc - mx);
      float s = e;
#pragma unroll
      for (int msk = 16; msk > 0; msk >>= 1) s += __shfl_xor(s, msk, 32);
      alL[i * 33 + j] = e / s;
    }
  }

  const int w = t >> 6, l = t & 63;
  const int n15 = l & 15, q = l >> 4;
  const int jh = w & 1, ibase = (w >> 1) * 16;
  const bool kact = (q < 2);

  // ---- phase 1: hp[ct][reg] for (c = ct*16+q*4+reg, j = jh*16+n15) ----
  f32x4 hp[4];
#pragma unroll
  for (int ct = 0; ct < 4; ++ct) hp[ct] = (f32x4){0.f, 0.f, 0.f, 0.f};
#pragma unroll
  for (int ct = 0; ct < 4; ++ct)
#pragma unroll
    for (int ks = 0; ks < 2; ++ks) {
      bf16x8 aF = *(const bf16x8*)(smem + W1H_OFF + (ct * 16 + n15) * 144 + ks * 64 + q * 16);
      bf16x8 bF = *(const bf16x8*)(smem + H3B_OFF + (jh * 16 + n15) * 144 + ks * 64 + q * 16);
      hp[ct] = __builtin_amdgcn_mfma_f32_16x16x32_bf16(aF, bF, hp[ct], 0, 0, 0);
    }
#pragma unroll
  for (int ct = 0; ct < 4; ++ct)
#pragma unroll
    for (int reg = 0; reg < 4; ++reg)
      hp[ct][reg] += b1[ct * 16 + q * 4 + reg];

  // hoisted fragments
  bf16x8 aL[4];
#pragma unroll
  for (int ct = 0; ct < 4; ++ct) {
    union { unsigned u[4]; bf16x8 h; } tmp;
    tmp.u[0] = tmp.u[1] = tmp.u[2] = tmp.u[3] = 0u;
    if (kact) {
      const unsigned* p = (const unsigned*)(smem + W1L_OFF) + (ct * 16 + n15) * 10 + q * 4;
      uint2e d0 = *(const uint2e*)p;
      uint2e d1 = *(const uint2e*)(p + 2);
      tmp.u[0] = d0.x; tmp.u[1] = d0.y; tmp.u[2] = d1.x; tmp.u[3] = d1.y;
    }
    aL[ct] = tmp.h;
  }
  bf16x8 w2F[2];
#pragma unroll
  for (int ks = 0; ks < 2; ++ks)
    w2F[ks] = *(const bf16x8*)(smem + W2P_OFF + n15 * 144 + ks * 64 + q * 16);
  float b2v[4];
#pragma unroll
  for (int reg = 0; reg < 4; ++reg) b2v[reg] = b2[q * 4 + reg];

  __syncthreads();  // alL complete before main loop reads it

  // ---- main i loop ----
  float agg[4] = {0.f, 0.f, 0.f, 0.f};
  char* wb = smem + MT_OFF + w * 2560;
  const float* alLf = (const float*)(smem + ALL_OFF);
#pragma unroll 1
  for (int it = 0; it < 16; ++it) {
    int ii = ibase + it;
    int r = ii * 32 + jh * 16 + n15;
    union { unsigned u[4]; bf16x8 h; } latF;
    latF.u[0] = latF.u[1] = latF.u[2] = latF.u[3] = 0u;
    if (kact) {
      const unsigned* p = latB_dw + r * 10 + q * 4;
      uint2e d0 = *(const uint2e*)p;
      uint2e d1 = *(const uint2e*)(p + 2);
      latF.u[0] = d0.x; latF.u[1] = d0.y; latF.u[2] = d1.x; latF.u[3] = d1.y;
    }
    f32x4 acc[4];
#pragma unroll
    for (int ct = 0; ct < 4; ++ct) {
      acc[ct] = (f32x4){0.f, 0.f, 0.f, 0.f};
      acc[ct] = __builtin_amdgcn_mfma_f32_16x16x32_bf16(aL[ct], latF.h, acc[ct], 0, 0, 0);
    }
    // lrelu + pack + pi-transpose write (per-wave private buffer, no barrier)
#pragma unroll
    for (int h = 0; h < 2; ++h) {
      float m0[4], m1[4];
#pragma unroll
      for (int reg = 0; reg < 4; ++reg) {
        float v0 = acc[2 * h][reg] + hp[2 * h][reg];
        float v1 = acc[2 * h + 1][reg] + hp[2 * h + 1][reg];
        m0[reg] = fmaxf(v0, 0.01f * v0);
        m1[reg] = fmaxf(v1, 0.01f * v1);
      }
      uint4e pk4;
      pk4.x = pkbf(m0[0], m0[1]); pk4.y = pkbf(m0[2], m0[3]);
      pk4.z = pkbf(m1[0], m1[1]); pk4.w = pkbf(m1[2], m1[3]);
      int qp = (2 * q + h) & 3;
      *(uint4e*)(wb + (q >> 1) * 1280 + n15 * 80 + qp * 16) = pk4;
    }
    // phase 3
    f32x4 msg = (f32x4){0.f, 0.f, 0.f, 0.f};
#pragma unroll
    for (int ks = 0; ks < 2; ++ks) {
      bf16x8 mF = *(const bf16x8*)(wb + ks * 1280 + n15 * 80 + q * 16);
      msg = __builtin_amdgcn_mfma_f32_16x16x32_bf16(w2F[ks], mF, msg, 0, 0, 0);
    }
    float aw = alLf[ii * 33 + jh * 16 + n15];
#pragma unroll
    for (int reg = 0; reg < 4; ++reg)
      agg[reg] = fmaf(aw, msg[reg] + b2v[reg], agg[reg]);
  }
  // park agg in own wave buffer
  {
    f32x4 av; av[0] = agg[0]; av[1] = agg[1]; av[2] = agg[2]; av[3] = agg[3];
    *(f32x4*)(wb + n15 * 80 + q * 16) = av;
  }
  __syncthreads();
  // combine wave pairs (i-low + i-high) and add q head
#pragma unroll
  for (int tt = 0; tt < 2; ++tt) {
    int idx = t + 256 * tt;
    int jg = idx >> 4, nn = idx & 15;
    int jh2 = jg >> 4, jl = jg & 15;
    float a0 = *(const float*)(smem + MT_OFF + jh2 * 2560 + jl * 80 + nn * 4);
    float a1 = *(const float*)(smem + MT_OFF + (jh2 + 2) * 2560 + jl * 80 + nn * 4);
    out[(size_t)b * 512 + idx] = a0 + a1 + qT[(size_t)nn * NROW + b32 + jg];
  }
}

}  // namespace

extern "C" void kernel_launch(void* const* d_in, const int* in_sizes, int n_in,
                              void* d_out, int out_size, void* d_ws, size_t ws_size,
                              hipStream_t stream) {
  (void)in_sizes; (void)n_in; (void)out_size; (void)ws_size;
  const float* inputs = (const float*)d_in[0];
  const float* hidden = (const float*)d_in[1];
  const float* eps    = (const float*)d_in[2];
  const float* fc1w   = (const float*)d_in[3];
  const float* fc1b   = (const float*)d_in[4];
  const float* wih    = (const float*)d_in[5];
  const float* whh    = (const float*)d_in[6];
  const float* bih    = (const float*)d_in[7];
  const float* bhh    = (const float*)d_in[8];
  const float* fc2w   = (const float*)d_in[9];
  const float* fc2b   = (const float*)d_in[10];
  const float* ew1    = (const float*)d_in[11];
  const float* eb1    = (const float*)d_in[12];
  const float* bng    = (const float*)d_in[13];
  const float* bnb    = (const float*)d_in[14];
  const float* ew2    = (const float*)d_in[15];
  const float* eb2    = (const float*)d_in[16];
  const float* w1     = (const float*)d_in[17];
  const float* b1     = (const float*)d_in[18];
  const float* w2     = (const float*)d_in[19];
  const float* b2     = (const float*)d_in[20];
  const float* wqw    = (const float*)d_in[21];
  const float* wkw    = (const float*)d_in[23];

  float* ws = (float*)d_ws;
  float* hT     = ws;                 // 2097152
  float* qT     = ws + 2097152;       // 524288
  float* qkT    = ws + 2621440;       // 524288
  float* z1T    = ws + 3670016;       // 2097152
  float* part   = ws + 5767168;       // 32768 used
  float* stat   = ws + 5832704;       // 128
  unsigned* latB16g = (unsigned*)(ws + 5832832);  // [N][256] u32 (bf16 pairs)

  float* out_q = (float*)d_out;             // 32768 x 16
  float* out_h = (float*)d_out + 524288;    // 32768 x 64

  hipLaunchKernelGGL(k_fgru, dim3(256), dim3(512), 0, stream,
                     inputs, hidden, fc1w, fc1b, wih, whh, bih, bhh, hT, out_h);
  hipLaunchKernelGGL(k_heads, dim3(256), dim3(256), 0, stream,
                     hT, fc2w, fc2b, wqw, wkw, ew1, eb1, qT, qkT, z1T, part);
  hipLaunchKernelGGL(k_bnstat, dim3(1), dim3(256), 0, stream, part, bng, bnb, stat);
  hipLaunchKernelGGL(k_emb_gemm, dim3(512), dim3(512), 0, stream, z1T, stat, ew2, eb2, eps, latB16g);
  hipLaunchKernelGGL(k_msg, dim3(1024), dim3(256), 0, stream,
                     latB16g, qkT, qT, out_h, w1, b1, w2, b2, out_q);
}

// Round 7
// 238.728 us; speedup vs baseline: 1.0758x; 1.0758x over previous
//
#include <hip/hip_runtime.h>
#include <math.h>

namespace {

constexpr int NROW = 32768;   // BS*A rows
constexpr int HDIM = 64;
constexpr int DH   = 512;     // latent half-dim

typedef __attribute__((ext_vector_type(8))) short bf16x8;
typedef __attribute__((ext_vector_type(4))) float f32x4;
typedef __attribute__((ext_vector_type(4))) unsigned uint4e;
typedef __attribute__((ext_vector_type(2))) unsigned uint2e;

__device__ __forceinline__ float sigmoidf_(float x) { return 1.f / (1.f + __expf(-x)); }
__device__ __forceinline__ float lrelu_(float x) { return x > 0.f ? x : 0.01f * x; }
// fast pack: round-half-up bf16 pair (a -> low16, b -> high16)
__device__ __forceinline__ unsigned pkbf(float a, float b) {
  unsigned ua = __float_as_uint(a) + 0x8000u;
  unsigned ub = __float_as_uint(b) + 0x8000u;
  return __builtin_amdgcn_perm(ub, ua, 0x07060302);
}

// K1+K2 fused: 512 threads, 8 waves x 16 rows; staging loads batched (unrolled).
__global__ __launch_bounds__(512, 1) void k_fgru(
    const float* __restrict__ in,      // [N][96]
    const float* __restrict__ hprev,   // [N][64]
    const float* __restrict__ fc1w, const float* __restrict__ fc1b,
    const float* __restrict__ wih, const float* __restrict__ whh,
    const float* __restrict__ bih, const float* __restrict__ bhh,
    float* __restrict__ hT, float* __restrict__ hout) {
  __shared__ char smem[73728];
  const int t = threadIdx.x;
  const int n0 = blockIdx.x * 128;
  short*    xS = (short*)smem;                 // [128][72] shorts
  unsigned* gU = (unsigned*)(smem + 18432);    // [6][64][36]
  float*    trF = (float*)(smem + 18432);      // [64][133] f32, overlays gU after GRU

  const float2* wih2 = (const float2*)wih;
  const float2* whh2 = (const float2*)whh;
  {  // gate weight staging: batched loads, then packs
    float2 wv[12];
#pragma unroll
    for (int i = 0; i < 12; ++i) {
      int idx = t + 512 * i;
      int row = idx >> 5, kp = idx & 31;
      wv[i] = wih2[row * 32 + kp];
    }
#pragma unroll
    for (int i = 0; i < 12; ++i) {
      int idx = t + 512 * i;
      int row = idx >> 5, kp = idx & 31;
      int gate = row >> 6, cl = row & 63;
      gU[(gate * 64 + cl) * 36 + kp] = pkbf(wv[i].x, wv[i].y);
    }
#pragma unroll
    for (int i = 0; i < 12; ++i) {
      int idx = t + 512 * i;
      int row = idx >> 5, kp = idx & 31;
      wv[i] = whh2[row * 32 + kp];
    }
#pragma unroll
    for (int i = 0; i < 12; ++i) {
      int idx = t + 512 * i;
      int row = idx >> 5, kp = idx & 31;
      int gate = row >> 6, cl = row & 63;
      gU[((gate + 3) * 64 + cl) * 36 + kp] = pkbf(wv[i].x, wv[i].y);
    }
  }

  const int w = t >> 6, l = t & 63;
  const int m = l & 15, g = l >> 4;
  const int rowA = n0 + w * 16 + m;      // A-operand row for this lane

  // ---- fc1 phase ----
  bf16x8 af[3];
#pragma unroll
  for (int ks = 0; ks < 3; ++ks) {
    const float4* p = (const float4*)(in + (size_t)rowA * 96 + ks * 32 + g * 8);
    float4 a = p[0], b = p[1];
    union { unsigned u[4]; bf16x8 h; } tw;
    tw.u[0] = pkbf(a.x, a.y); tw.u[1] = pkbf(a.z, a.w);
    tw.u[2] = pkbf(b.x, b.y); tw.u[3] = pkbf(b.z, b.w);
    af[ks] = tw.h;
  }
  {
    f32x4 accx[4];
#pragma unroll
    for (int ct = 0; ct < 4; ++ct) accx[ct] = (f32x4){0.f, 0.f, 0.f, 0.f};
#pragma unroll
    for (int ct = 0; ct < 4; ++ct)
#pragma unroll
      for (int ks = 0; ks < 3; ++ks) {
        const float4* p = (const float4*)(fc1w + (ct * 16 + m) * 96 + ks * 32 + g * 8);
        float4 a = p[0], b = p[1];
        union { unsigned u[4]; bf16x8 h; } tw;
        tw.u[0] = pkbf(a.x, a.y); tw.u[1] = pkbf(a.z, a.w);
        tw.u[2] = pkbf(b.x, b.y); tw.u[3] = pkbf(b.z, b.w);
        accx[ct] = __builtin_amdgcn_mfma_f32_16x16x32_bf16(af[ks], tw.h, accx[ct], 0, 0, 0);
      }
#pragma unroll
    for (int ct = 0; ct < 4; ++ct) {
      int c = ct * 16 + m;
      float bc = fc1b[c];
#pragma unroll
      for (int reg = 0; reg < 4; ++reg) {
        int nl = w * 16 + g * 4 + reg;
        float v = fmaxf(accx[ct][reg] + bc, 0.f);
        xS[nl * 72 + c] = (short)((__float_as_uint(v) + 0x8000u) >> 16);
      }
    }
  }
  __syncthreads();   // xS ready + gU ready

  // ---- GRU phase ----
  bf16x8 ax[2], ah[2];
#pragma unroll
  for (int ks = 0; ks < 2; ++ks) {
    ax[ks] = *(const bf16x8*)(xS + (w * 16 + m) * 72 + ks * 32 + g * 8);
    const float4* p = (const float4*)(hprev + (size_t)rowA * 64 + ks * 32 + g * 8);
    float4 a = p[0], b = p[1];
    union { unsigned u[4]; bf16x8 h; } tw;
    tw.u[0] = pkbf(a.x, a.y); tw.u[1] = pkbf(a.z, a.w);
    tw.u[2] = pkbf(b.x, b.y); tw.u[3] = pkbf(b.z, b.w);
    ah[ks] = tw.h;
  }
  const short* gS = (const short*)gU;
  float hc[4][4];
#pragma unroll 1
  for (int ct = 0; ct < 4; ++ct) {
    f32x4 a_ir = (f32x4){0.f,0.f,0.f,0.f}, a_iz = (f32x4){0.f,0.f,0.f,0.f},
          a_in = (f32x4){0.f,0.f,0.f,0.f}, a_hr = (f32x4){0.f,0.f,0.f,0.f},
          a_hz = (f32x4){0.f,0.f,0.f,0.f}, a_hn = (f32x4){0.f,0.f,0.f,0.f};
    int crow = ct * 16 + m;
#pragma unroll
    for (int ks = 0; ks < 2; ++ks) {
      bf16x8 b0 = *(const bf16x8*)(gS + (0 * 64 + crow) * 72 + ks * 32 + g * 8);
      bf16x8 b1 = *(const bf16x8*)(gS + (1 * 64 + crow) * 72 + ks * 32 + g * 8);
      bf16x8 b2 = *(const bf16x8*)(gS + (2 * 64 + crow) * 72 + ks * 32 + g * 8);
      bf16x8 b3 = *(const bf16x8*)(gS + (3 * 64 + crow) * 72 + ks * 32 + g * 8);
      bf16x8 b4 = *(const bf16x8*)(gS + (4 * 64 + crow) * 72 + ks * 32 + g * 8);
      bf16x8 b5 = *(const bf16x8*)(gS + (5 * 64 + crow) * 72 + ks * 32 + g * 8);
      a_ir = __builtin_amdgcn_mfma_f32_16x16x32_bf16(ax[ks], b0, a_ir, 0, 0, 0);
      a_iz = __builtin_amdgcn_mfma_f32_16x16x32_bf16(ax[ks], b1, a_iz, 0, 0, 0);
      a_in = __builtin_amdgcn_mfma_f32_16x16x32_bf16(ax[ks], b2, a_in, 0, 0, 0);
      a_hr = __builtin_amdgcn_mfma_f32_16x16x32_bf16(ah[ks], b3, a_hr, 0, 0, 0);
      a_hz = __builtin_amdgcn_mfma_f32_16x16x32_bf16(ah[ks], b4, a_hz, 0, 0, 0);
      a_hn = __builtin_amdgcn_mfma_f32_16x16x32_bf16(ah[ks], b5, a_hn, 0, 0, 0);
    }
    float bir = bih[crow], biz = bih[64 + crow], bin = bih[128 + crow];
    float bhr = bhh[crow], bhz = bhh[64 + crow], bhn = bhh[128 + crow];
#pragma unroll
    for (int reg = 0; reg < 4; ++reg) {
      int nl = w * 16 + g * 4 + reg;
      float hv = hprev[(size_t)(n0 + nl) * 64 + crow];
      float r  = sigmoidf_(a_ir[reg] + bir + a_hr[reg] + bhr);
      float z  = sigmoidf_(a_iz[reg] + biz + a_hz[reg] + bhz);
      float nn = tanhf(a_in[reg] + bin + r * (a_hn[reg] + bhn));
      hc[ct][reg] = (1.f - z) * nn + z * hv;
    }
  }
  __syncthreads();   // all waves done reading gU before trF overlay
#pragma unroll
  for (int ct = 0; ct < 4; ++ct)
#pragma unroll
    for (int reg = 0; reg < 4; ++reg)
      trF[(ct * 16 + m) * 133 + w * 16 + g * 4 + reg] = hc[ct][reg];
  __syncthreads();
#pragma unroll
  for (int i = 0; i < 16; ++i) {
    int idx = t + 512 * i;
    int nl = idx & 127, cl = idx >> 7;
    hT[(size_t)cl * NROW + n0 + nl] = trF[cl * 133 + nl];
  }
#pragma unroll
  for (int i = 0; i < 16; ++i) {
    int idx = t + 512 * i;
    int c = idx & 63, nl = idx >> 6;
    hout[(size_t)(n0 + nl) * 64 + c] = trF[c * 133 + nl];
  }
}

// K3 (MFMA): 96-channel fused head GEMM (fc2 16 + qk 16 + ew1 64), K=64.
// Staging de-serialized: batched h loads; copy-rows pass + dedicated qk pass.
__global__ __launch_bounds__(256) void k_heads(const float* __restrict__ hT,
    const float* __restrict__ fc2w, const float* __restrict__ fc2b,
    const float* __restrict__ wqw, const float* __restrict__ wkw,
    const float* __restrict__ ew1, const float* __restrict__ eb1,
    float* __restrict__ qT, float* __restrict__ qkT, float* __restrict__ z1T,
    float* __restrict__ part) {
  __shared__ char smem[36864];
  const int t = threadIdx.x;
  const int n0 = blockIdx.x * 128;
  unsigned* hU = (unsigned*)smem;                 // [128][36]
  unsigned* wU = (unsigned*)(smem + 18432);       // [96][36]
  float* sp1 = (float*)(smem + 18432 + 13824);    // [4][64]
  float* sp2 = sp1 + 256;                         // [4][64]
  const float qs = 0.17677669529663687f;          // 1/sqrt(32)

  {  // h staging: batched loads
    float va[16], vb[16];
#pragma unroll
    for (int i = 0; i < 16; ++i) {
      int idx = t + 256 * i;
      int nl = idx & 127, kp = idx >> 7;
      va[i] = hT[(size_t)(2 * kp) * NROW + n0 + nl];
      vb[i] = hT[(size_t)(2 * kp + 1) * NROW + n0 + nl];
    }
#pragma unroll
    for (int i = 0; i < 16; ++i) {
      int idx = t + 256 * i;
      int nl = idx & 127, kp = idx >> 7;
      hU[nl * 36 + kp] = pkbf(va[i], vb[i]);
    }
  }
  {  // weight copies: fc2 (wU rows 0..15) + ew1 (wU rows 32..95)
    float2 wv[10];
#pragma unroll
    for (int i = 0; i < 10; ++i) {
      int idx = t + 256 * i;            // 0..2559
      int kp = idx & 31, cl = idx >> 5; // 0..79
      const float* src = (cl < 16) ? (fc2w + cl * 64) : (ew1 + (cl - 16) * 64);
      wv[i] = *(const float2*)(src + 2 * kp);
    }
#pragma unroll
    for (int i = 0; i < 10; ++i) {
      int idx = t + 256 * i;
      int kp = idx & 31, cl = idx >> 5;
      int dst = (cl < 16) ? cl : (cl + 16);
      wU[dst * 36 + kp] = pkbf(wv[i].x, wv[i].y);
    }
  }
  {  // qk rows (wU rows 16..31): qs * Wk^T Wq, inner loop unrolled
    int kp = t & 31, ll = t >> 5;   // ll 0..7; rows ll, ll+8
#pragma unroll
    for (int h = 0; h < 2; ++h) {
      int row = ll + 8 * h;
      float s0 = 0.f, s1 = 0.f;
#pragma unroll
      for (int a = 0; a < 32; ++a) {
        float wk = wkw[a * 16 + row];
        s0 = fmaf(wk, wqw[a * 64 + 2 * kp], s0);
        s1 = fmaf(wk, wqw[a * 64 + 2 * kp + 1], s1);
      }
      wU[(16 + row) * 36 + kp] = pkbf(s0 * qs, s1 * qs);
    }
  }
  __syncthreads();

  const int w = t >> 6, l = t & 63;
  const int m = l & 15, g = l >> 4;
  const short* sH = (const short*)hU;
  const short* sW = (const short*)wU;

  bf16x8 af[2][2];
#pragma unroll
  for (int mt = 0; mt < 2; ++mt)
#pragma unroll
    for (int ks = 0; ks < 2; ++ks)
      af[mt][ks] = *(const bf16x8*)(sH + (w * 32 + mt * 16 + m) * 72 + ks * 32 + g * 8);

  f32x4 acc[2][6];
#pragma unroll
  for (int mt = 0; mt < 2; ++mt)
#pragma unroll
    for (int ct = 0; ct < 6; ++ct) acc[mt][ct] = (f32x4){0.f, 0.f, 0.f, 0.f};
#pragma unroll
  for (int ct = 0; ct < 6; ++ct)
#pragma unroll
    for (int ks = 0; ks < 2; ++ks) {
      bf16x8 bw = *(const bf16x8*)(sW + (ct * 16 + m) * 72 + ks * 32 + g * 8);
#pragma unroll
      for (int mt = 0; mt < 2; ++mt)
        acc[mt][ct] = __builtin_amdgcn_mfma_f32_16x16x32_bf16(af[mt][ks], bw, acc[mt][ct], 0, 0, 0);
    }

  float s1[4], s2[4];
#pragma unroll
  for (int zt = 0; zt < 4; ++zt) { s1[zt] = 0.f; s2[zt] = 0.f; }
#pragma unroll
  for (int mt = 0; mt < 2; ++mt) {
    int nb = n0 + w * 32 + mt * 16 + g * 4;
    {  // q head: c = m
      float bc = fc2b[m];
      f32x4 v;
#pragma unroll
      for (int reg = 0; reg < 4; ++reg) v[reg] = acc[mt][0][reg] + bc;
      *(f32x4*)(qT + (size_t)m * NROW + nb) = v;
    }
    // qk head: l' = m, no bias
    *(f32x4*)(qkT + (size_t)m * NROW + nb) = acc[mt][1];
#pragma unroll
    for (int ct = 2; ct < 6; ++ct) {  // z1 head: z = (ct-2)*16 + m
      int z = (ct - 2) * 16 + m;
      float bc = eb1[z];
      f32x4 v;
#pragma unroll
      for (int reg = 0; reg < 4; ++reg) {
        float zv = acc[mt][ct][reg] + bc;
        v[reg] = zv;
        s1[ct - 2] += zv;
        s2[ct - 2] = fmaf(zv, zv, s2[ct - 2]);
      }
      *(f32x4*)(z1T + (size_t)z * NROW + nb) = v;
    }
  }
#pragma unroll
  for (int zt = 0; zt < 4; ++zt) {
    s1[zt] += __shfl_down(s1[zt], 16, 64);
    s1[zt] += __shfl_down(s1[zt], 32, 64);
    s2[zt] += __shfl_down(s2[zt], 16, 64);
    s2[zt] += __shfl_down(s2[zt], 32, 64);
  }
  if (l < 16) {
#pragma unroll
    for (int zt = 0; zt < 4; ++zt) {
      sp1[w * 64 + zt * 16 + m] = s1[zt];
      sp2[w * 64 + zt * 16 + m] = s2[zt];
    }
  }
  __syncthreads();
  if (t < 64) {
    float a1 = sp1[t] + sp1[64 + t] + sp1[128 + t] + sp1[192 + t];
    float a2 = sp2[t] + sp2[64 + t] + sp2[128 + t] + sp2[192 + t];
    part[(size_t)blockIdx.x * 128 + t] = a1;
    part[(size_t)blockIdx.x * 128 + 64 + t] = a2;
  }
}

// K4: block 0 = BN stats (4-way sliced); blocks 1..64 = pack ew2 f32 -> bf16
// (16 rows of 64 each) into ew2b [1024][32] u32 for the fused k_msg GEMM.
__global__ __launch_bounds__(256) void k_bnstat(const float* __restrict__ part,
    const float* __restrict__ bng, const float* __restrict__ bnb,
    const float* __restrict__ ew2,
    float* __restrict__ stat, unsigned* __restrict__ ew2b) {
  if (blockIdx.x == 0) {
    __shared__ float red[512];
    const int t = threadIdx.x;        // 256
    const int c = t & 63, q = t >> 6; // q 0..3
    float s1 = 0.f, s2 = 0.f;
#pragma unroll 4
    for (int b = q; b < 256; b += 4) {
      s1 += part[(size_t)b * 128 + c];
      s2 += part[(size_t)b * 128 + 64 + c];
    }
    red[q * 64 + c] = s1;
    red[256 + q * 64 + c] = s2;
    __syncthreads();
    if (t < 64) {
      float a1 = red[t] + red[64 + t] + red[128 + t] + red[192 + t];
      float a2 = red[256 + t] + red[320 + t] + red[384 + t] + red[448 + t];
      float mean = a1 * (1.f / NROW);
      float var = a2 * (1.f / NROW) - mean * mean;
      float rstd = rsqrtf(var + 1e-5f);
      float sc = bng[t] * rstd;
      stat[t] = sc;
      stat[64 + t] = bnb[t] - mean * sc;
    }
  } else {
    const int rb = blockIdx.x - 1;    // 0..63 -> rows rb*16 .. rb*16+15
    const int t = threadIdx.x;
#pragma unroll
    for (int it = 0; it < 2; ++it) {
      int id2 = t + 256 * it;          // 0..511 col-pairs
      int r = rb * 16 + (id2 >> 5);    // row
      int cp = id2 & 31;               // col-pair 0..31
      float2 v = *(const float2*)(ew2 + (size_t)r * 64 + 2 * cp);
      ew2b[(size_t)r * 32 + cp] = pkbf(v.x, v.y);
    }
  }
}

// K7 (fused): one block per b. Latent GEMM (32x1024, K=64) computed IN-BLOCK
// into LDS latB (no global latent round-trip), then logits+softmax+msg as before.
constexpr int LATB_OFF = 0;        // [1024][20] bf16, 40B rows (r = i*32+j)
constexpr int H3B_OFF  = 40960;    // [32][72] bf16, 144B rows
constexpr int W1H_OFF  = 45568;    // [64][72] bf16
constexpr int W1L_OFF  = 54784;    // [64][20] bf16
constexpr int W2P_OFF  = 57344;    // [16][72] bf16 (pi-permuted c)
constexpr int ALL_OFF  = 59648;    // [32][33] f32 alpha
constexpr int MT_OFF   = 63872;    // 4 waves x 2560B private transpose buf; xz overlay pre-main-loop
constexpr int QKL_OFF  = 74112;    // [32][20] f32 qk
__global__ __launch_bounds__(256, 1) void k_msg(
    const unsigned* __restrict__ ew2b, const float* __restrict__ stat,
    const float* __restrict__ z1T, const float* __restrict__ eb2,
    const float* __restrict__ eps,
    const float* __restrict__ qkT,
    const float* __restrict__ qT, const float* __restrict__ hrow,
    const float* __restrict__ w1, const float* __restrict__ b1,
    const float* __restrict__ w2, const float* __restrict__ b2,
    float* __restrict__ out) {
  __shared__ char smem[76672];
  const int t = threadIdx.x;
  const int b = blockIdx.x;
  const int b32 = b * 32;
  unsigned* latB_dw = (unsigned*)(smem + LATB_OFF);

  const int w = t >> 6, l = t & 63;
  const int m = l & 15, g = l >> 4;

  // ---- staging ----
  {  // xz: z1 slice [32 rows][64 k] -> BN+lrelu -> bf16 @ MT_OFF overlay
    short* xz = (short*)(smem + MT_OFF);
    float zv[8];
#pragma unroll
    for (int it = 0; it < 8; ++it) {
      int idx = t + 256 * it;          // 0..2047
      int i = idx & 31, c = idx >> 5;  // row 0..31, col 0..63
      zv[it] = z1T[(size_t)c * NROW + b32 + i];
    }
#pragma unroll
    for (int it = 0; it < 8; ++it) {
      int idx = t + 256 * it;
      int i = idx & 31, c = idx >> 5;
      float v = lrelu_(fmaf(stat[c], zv[it], stat[64 + c]));
      xz[i * 72 + c] = (short)((__float_as_uint(v) + 0x8000u) >> 16);
    }
  }
  {  // qkL[i][l] from qkT
    float* qkL = (float*)(smem + QKL_OFF);
    int i = t & 31;
    float v0 = qkT[(size_t)((t >> 5)) * NROW + b32 + i];
    float v1 = qkT[(size_t)((t >> 5) + 8) * NROW + b32 + i];
    qkL[i * 20 + (t >> 5)] = v0;
    qkL[i * 20 + (t >> 5) + 8] = v1;
  }
  {  // h3B[j][k] bf16 from row-major h
    int cp = t & 31, jj = t >> 5;
    const float2* h2 = (const float2*)hrow;
    float2 hv[4];
#pragma unroll
    for (int it = 0; it < 4; ++it)
      hv[it] = h2[((size_t)(b32 + jj + 8 * it) * 64 + 2 * cp) >> 1];
    unsigned* dst = (unsigned*)(smem + H3B_OFF);
#pragma unroll
    for (int it = 0; it < 4; ++it)
      dst[(jj + 8 * it) * 36 + cp] = pkbf(hv[it].x, hv[it].y);
  }
  {  // w1hL[c][k] (k<64)
    int kp = t & 31, cc = t >> 5;
    const float2* w12 = (const float2*)w1;
    float2 wv[8];
#pragma unroll
    for (int it = 0; it < 8; ++it)
      wv[it] = w12[((cc + 8 * it) * 80 + 2 * kp) >> 1];
    unsigned* dst = (unsigned*)(smem + W1H_OFF);
#pragma unroll
    for (int it = 0; it < 8; ++it)
      dst[(cc + 8 * it) * 36 + kp] = pkbf(wv[it].x, wv[it].y);
  }
  {  // w1latL[c][l]
    int lp = t & 7, cc = t >> 3;
    const float2* w12 = (const float2*)w1;
    float2 wv[2];
#pragma unroll
    for (int it = 0; it < 2; ++it)
      wv[it] = w12[((cc + 32 * it) * 80 + 64 + 2 * lp) >> 1];
    unsigned* dst = (unsigned*)(smem + W1L_OFF);
#pragma unroll
    for (int it = 0; it < 2; ++it)
      dst[(cc + 32 * it) * 10 + lp] = pkbf(wv[it].x, wv[it].y);
  }
  {  // w2P[nn][p] = w2[nn][c(p)], c(p) = ((p>>2)&3)*16 + (p>>4)*4 + (p&3)
    int pp = t & 31, nn = t >> 5;
    const float2* w22 = (const float2*)w2;
    int p = 2 * pp;
    int c = ((p >> 2) & 3) * 16 + (p >> 4) * 4 + (p & 3);
    float2 wv0 = w22[(nn * 64 + c) >> 1];
    float2 wv1 = w22[((nn + 8) * 64 + c) >> 1];
    unsigned* dst = (unsigned*)(smem + W2P_OFF);
    dst[nn * 36 + pp] = pkbf(wv0.x, wv0.y);
    dst[(nn + 8) * 36 + pp] = pkbf(wv1.x, wv1.y);
  }
  __syncthreads();   // all staging (incl. xz) visible

  // ---- latent GEMM: lat[32][512] -> latB (LDS), wave w owns j-tiles w*8..w*8+7 ----
  {
    const short* xzS = (const short*)(smem + MT_OFF);
    bf16x8 afz[2][2];
#pragma unroll
    for (int mt = 0; mt < 2; ++mt)
#pragma unroll
      for (int ks = 0; ks < 2; ++ks)
        afz[mt][ks] = *(const bf16x8*)(xzS + (mt * 16 + m) * 72 + ks * 32 + g * 8);
    const uint4e* w4 = (const uint4e*)ew2b;
    const float stdfloor = 0.04472135955f;   // sqrt(0.002)
#pragma unroll 2
    for (int ci8 = 0; ci8 < 8; ++ci8) {
      int ci = w * 8 + ci8;                  // j-tile 0..31
      int c = ci * 16 + m;                   // latent column
      union { uint4e u; bf16x8 h; } bmu[2], blv[2];
#pragma unroll
      for (int ks = 0; ks < 2; ++ks) {
        bmu[ks].u = w4[(size_t)(ci * 16 + m) * 8 + ks * 4 + g];
        blv[ks].u = w4[(size_t)(512 + ci * 16 + m) * 8 + ks * 4 + g];
      }
      float ep[2][4];
#pragma unroll
      for (int mt = 0; mt < 2; ++mt)
#pragma unroll
        for (int reg = 0; reg < 4; ++reg)
          ep[mt][reg] = eps[(size_t)(b32 + mt * 16 + g * 4 + reg) * 512 + c];
      f32x4 accm[2], accl[2];
#pragma unroll
      for (int mt = 0; mt < 2; ++mt) {
        accm[mt] = (f32x4){0.f, 0.f, 0.f, 0.f};
        accl[mt] = (f32x4){0.f, 0.f, 0.f, 0.f};
      }
#pragma unroll
      for (int ks = 0; ks < 2; ++ks)
#pragma unroll
        for (int mt = 0; mt < 2; ++mt) {
          accm[mt] = __builtin_amdgcn_mfma_f32_16x16x32_bf16(afz[mt][ks], bmu[ks].h, accm[mt], 0, 0, 0);
          accl[mt] = __builtin_amdgcn_mfma_f32_16x16x32_bf16(afz[mt][ks], blv[ks].h, accl[mt], 0, 0, 0);
        }
      float ebm = eb2[c], ebl = eb2[DH + c];
#pragma unroll
      for (int mt = 0; mt < 2; ++mt)
#pragma unroll
        for (int reg = 0; reg < 4; ++reg) {
          float mu = accm[mt][reg] + ebm;
          float lv = accl[mt][reg] + ebl;
          float sd = fmaxf(__expf(0.5f * lv), stdfloor);
          float lat = fmaf(sd, ep[mt][reg], mu);
          float lat2 = __shfl_xor(lat, 1, 64);
          if (!(m & 1)) {
            int i = mt * 16 + g * 4 + reg;
            latB_dw[(i * 32 + ci) * 10 + (m >> 1)] = pkbf(lat, lat2);
          }
        }
    }
  }
  __syncthreads();   // latB complete before logits

  // ---- logits + softmax -> alL (reads latB + qkL) ----
  {
    const float* qkL = (const float*)(smem + QKL_OFF);
    float* alL = (float*)(smem + ALL_OFF);
#pragma unroll 1
    for (int p = 0; p < 4; ++p) {
      int i = (t >> 5) + 8 * p;
      int j = t & 31;
      const unsigned* lr = latB_dw + (i * 32 + j) * 10;
      float acc = 0.f;
#pragma unroll
      for (int d = 0; d < 8; ++d) {
        unsigned u = lr[d];
        float lo = __uint_as_float(u << 16);
        float hi = __uint_as_float(u & 0xffff0000u);
        acc = fmaf(lo, qkL[i * 20 + 2 * d], acc);
        acc = fmaf(hi, qkL[i * 20 + 2 * d + 1], acc);
      }
      if (j == i) acc = -1e9f;
      float mx = acc;
#pragma unroll
      for (int msk = 16; msk > 0; msk >>= 1) mx = fmaxf(mx, __shfl_xor(mx, msk, 32));
      float e = __expf(acc - mx);
      float s = e;
#pragma unroll
      for (int msk = 16; msk > 0; msk >>= 1) s += __shfl_xor(s, msk, 32);
      alL[i * 33 + j] = e / s;
    }
  }

  const int n15 = l & 15, q = l >> 4;
  const int jh = w & 1, ibase = (w >> 1) * 16;
  const bool kact = (q < 2);

  // ---- phase 1: hp[ct][reg] for (c = ct*16+q*4+reg, j = jh*16+n15) ----
  f32x4 hp[4];
#pragma unroll
  for (int ct = 0; ct < 4; ++ct) hp[ct] = (f32x4){0.f, 0.f, 0.f, 0.f};
#pragma unroll
  for (int ct = 0; ct < 4; ++ct)
#pragma unroll
    for (int ks = 0; ks < 2; ++ks) {
      bf16x8 aF = *(const bf16x8*)(smem + W1H_OFF + (ct * 16 + n15) * 144 + ks * 64 + q * 16);
      bf16x8 bF = *(const bf16x8*)(smem + H3B_OFF + (jh * 16 + n15) * 144 + ks * 64 + q * 16);
      hp[ct] = __builtin_amdgcn_mfma_f32_16x16x32_bf16(aF, bF, hp[ct], 0, 0, 0);
    }
#pragma unroll
  for (int ct = 0; ct < 4; ++ct)
#pragma unroll
    for (int reg = 0; reg < 4; ++reg)
      hp[ct][reg] += b1[ct * 16 + q * 4 + reg];

  // hoisted fragments
  bf16x8 aL[4];
#pragma unroll
  for (int ct = 0; ct < 4; ++ct) {
    union { unsigned u[4]; bf16x8 h; } tmp;
    tmp.u[0] = tmp.u[1] = tmp.u[2] = tmp.u[3] = 0u;
    if (kact) {
      const unsigned* p = (const unsigned*)(smem + W1L_OFF) + (ct * 16 + n15) * 10 + q * 4;
      uint2e d0 = *(const uint2e*)p;
      uint2e d1 = *(const uint2e*)(p + 2);
      tmp.u[0] = d0.x; tmp.u[1] = d0.y; tmp.u[2] = d1.x; tmp.u[3] = d1.y;
    }
    aL[ct] = tmp.h;
  }
  bf16x8 w2F[2];
#pragma unroll
  for (int ks = 0; ks < 2; ++ks)
    w2F[ks] = *(const bf16x8*)(smem + W2P_OFF + n15 * 144 + ks * 64 + q * 16);
  float b2v[4];
#pragma unroll
  for (int reg = 0; reg < 4; ++reg) b2v[reg] = b2[q * 4 + reg];

  __syncthreads();  // alL complete before main loop reads it (xz dead from here)

  // ---- main i loop ----
  float agg[4] = {0.f, 0.f, 0.f, 0.f};
  char* wb = smem + MT_OFF + w * 2560;
  const float* alLf = (const float*)(smem + ALL_OFF);
#pragma unroll 1
  for (int it = 0; it < 16; ++it) {
    int ii = ibase + it;
    int r = ii * 32 + jh * 16 + n15;
    union { unsigned u[4]; bf16x8 h; } latF;
    latF.u[0] = latF.u[1] = latF.u[2] = latF.u[3] = 0u;
    if (kact) {
      const unsigned* p = latB_dw + r * 10 + q * 4;
      uint2e d0 = *(const uint2e*)p;
      uint2e d1 = *(const uint2e*)(p + 2);
      latF.u[0] = d0.x; latF.u[1] = d0.y; latF.u[2] = d1.x; latF.u[3] = d1.y;
    }
    f32x4 acc[4];
#pragma unroll
    for (int ct = 0; ct < 4; ++ct) {
      acc[ct] = (f32x4){0.f, 0.f, 0.f, 0.f};
      acc[ct] = __builtin_amdgcn_mfma_f32_16x16x32_bf16(aL[ct], latF.h, acc[ct], 0, 0, 0);
    }
    // lrelu + pack + pi-transpose write (per-wave private buffer, no barrier)
#pragma unroll
    for (int h = 0; h < 2; ++h) {
      float m0[4], m1[4];
#pragma unroll
      for (int reg = 0; reg < 4; ++reg) {
        float v0 = acc[2 * h][reg] + hp[2 * h][reg];
        float v1 = acc[2 * h + 1][reg] + hp[2 * h + 1][reg];
        m0[reg] = fmaxf(v0, 0.01f * v0);
        m1[reg] = fmaxf(v1, 0.01f * v1);
      }
      uint4e pk4;
      pk4.x = pkbf(m0[0], m0[1]); pk4.y = pkbf(m0[2], m0[3]);
      pk4.z = pkbf(m1[0], m1[1]); pk4.w = pkbf(m1[2], m1[3]);
      int qp = (2 * q + h) & 3;
      *(uint4e*)(wb + (q >> 1) * 1280 + n15 * 80 + qp * 16) = pk4;
    }
    // phase 3
    f32x4 msg = (f32x4){0.f, 0.f, 0.f, 0.f};
#pragma unroll
    for (int ks = 0; ks < 2; ++ks) {
      bf16x8 mF = *(const bf16x8*)(wb + ks * 1280 + n15 * 80 + q * 16);
      msg = __builtin_amdgcn_mfma_f32_16x16x32_bf16(w2F[ks], mF, msg, 0, 0, 0);
    }
    float aw = alLf[ii * 33 + jh * 16 + n15];
#pragma unroll
    for (int reg = 0; reg < 4; ++reg)
      agg[reg] = fmaf(aw, msg[reg] + b2v[reg], agg[reg]);
  }
  // park agg in own wave buffer
  {
    f32x4 av; av[0] = agg[0]; av[1] = agg[1]; av[2] = agg[2]; av[3] = agg[3];
    *(f32x4*)(wb + n15 * 80 + q * 16) = av;
  }
  __syncthreads();
  // combine wave pairs (i-low + i-high) and add q head
#pragma unroll
  for (int tt = 0; tt < 2; ++tt) {
    int idx = t + 256 * tt;
    int jg = idx >> 4, nn = idx & 15;
    int jh2 = jg >> 4, jl = jg & 15;
    float a0 = *(const float*)(smem + MT_OFF + jh2 * 2560 + jl * 80 + nn * 4);
    float a1 = *(const float*)(smem + MT_OFF + (jh2 + 2) * 2560 + jl * 80 + nn * 4);
    out[(size_t)b * 512 + idx] = a0 + a1 + qT[(size_t)nn * NROW + b32 + jg];
  }
}

}  // namespace

extern "C" void kernel_launch(void* const* d_in, const int* in_sizes, int n_in,
                              void* d_out, int out_size, void* d_ws, size_t ws_size,
                              hipStream_t stream) {
  (void)in_sizes; (void)n_in; (void)out_size; (void)ws_size;
  const float* inputs = (const float*)d_in[0];
  const float* hidden = (const float*)d_in[1];
  const float* eps    = (const float*)d_in[2];
  const float* fc1w   = (const float*)d_in[3];
  const float* fc1b   = (const float*)d_in[4];
  const float* wih    = (const float*)d_in[5];
  const float* whh    = (const float*)d_in[6];
  const float* bih    = (const float*)d_in[7];
  const float* bhh    = (const float*)d_in[8];
  const float* fc2w   = (const float*)d_in[9];
  const float* fc2b   = (const float*)d_in[10];
  const float* ew1    = (const float*)d_in[11];
  const float* eb1    = (const float*)d_in[12];
  const float* bng    = (const float*)d_in[13];
  const float* bnb    = (const float*)d_in[14];
  const float* ew2    = (const float*)d_in[15];
  const float* eb2    = (const float*)d_in[16];
  const float* w1     = (const float*)d_in[17];
  const float* b1     = (const float*)d_in[18];
  const float* w2     = (const float*)d_in[19];
  const float* b2     = (const float*)d_in[20];
  const float* wqw    = (const float*)d_in[21];
  const float* wkw    = (const float*)d_in[23];

  float* ws = (float*)d_ws;
  float* hT     = ws;                 // 2097152
  float* qT     = ws + 2097152;       // 524288
  float* qkT    = ws + 2621440;       // 524288
  float* z1T    = ws + 3670016;       // 2097152
  float* part   = ws + 5767168;       // 32768 used
  float* stat   = ws + 5832704;       // 128
  unsigned* ew2b = (unsigned*)(ws + 5832832);  // [1024][32] u32 (bf16-packed ew2)

  float* out_q = (float*)d_out;             // 32768 x 16
  float* out_h = (float*)d_out + 524288;    // 32768 x 64

  hipLaunchKernelGGL(k_fgru, dim3(256), dim3(512), 0, stream,
                     inputs, hidden, fc1w, fc1b, wih, whh, bih, bhh, hT, out_h);
  hipLaunchKernelGGL(k_heads, dim3(256), dim3(256), 0, stream,
                     hT, fc2w, fc2b, wqw, wkw, ew1, eb1, qT, qkT, z1T, part);
  hipLaunchKernelGGL(k_bnstat, dim3(65), dim3(256), 0, stream, part, bng, bnb, ew2, stat, ew2b);
  hipLaunchKernelGGL(k_msg, dim3(1024), dim3(256), 0, stream,
                     ew2b, stat, z1T, eb2, eps, qkT, qT, out_h, w1, b1, w2, b2, out_q);
}

// Round 8
// 227.363 us; speedup vs baseline: 1.1296x; 1.0500x over previous
//
#include <hip/hip_runtime.h>
#include <math.h>

namespace {

constexpr int NROW = 32768;   // BS*A rows
constexpr int HDIM = 64;
constexpr int DH   = 512;     // latent half-dim

typedef __attribute__((ext_vector_type(8))) short bf16x8;
typedef __attribute__((ext_vector_type(4))) float f32x4;
typedef __attribute__((ext_vector_type(4))) unsigned uint4e;
typedef __attribute__((ext_vector_type(2))) unsigned uint2e;

__device__ __forceinline__ float sigmoidf_(float x) { return 1.f / (1.f + __expf(-x)); }
__device__ __forceinline__ float lrelu_(float x) { return x > 0.f ? x : 0.01f * x; }
// fast pack: round-half-up bf16 pair (a -> low16, b -> high16)
__device__ __forceinline__ unsigned pkbf(float a, float b) {
  unsigned ua = __float_as_uint(a) + 0x8000u;
  unsigned ub = __float_as_uint(b) + 0x8000u;
  return __builtin_amdgcn_perm(ub, ua, 0x07060302);
}

// K1+K2 fused: 512 threads, 8 waves x 16 rows; staging loads batched (unrolled).
__global__ __launch_bounds__(512, 1) void k_fgru(
    const float* __restrict__ in,      // [N][96]
    const float* __restrict__ hprev,   // [N][64]
    const float* __restrict__ fc1w, const float* __restrict__ fc1b,
    const float* __restrict__ wih, const float* __restrict__ whh,
    const float* __restrict__ bih, const float* __restrict__ bhh,
    float* __restrict__ hT, float* __restrict__ hout) {
  __shared__ char smem[73728];
  const int t = threadIdx.x;
  const int n0 = blockIdx.x * 128;
  short*    xS = (short*)smem;                 // [128][72] shorts
  unsigned* gU = (unsigned*)(smem + 18432);    // [6][64][36]
  float*    trF = (float*)(smem + 18432);      // [64][133] f32, overlays gU after GRU

  const float2* wih2 = (const float2*)wih;
  const float2* whh2 = (const float2*)whh;
  {  // gate weight staging: batched loads, then packs
    float2 wv[12];
#pragma unroll
    for (int i = 0; i < 12; ++i) {
      int idx = t + 512 * i;
      int row = idx >> 5, kp = idx & 31;
      wv[i] = wih2[row * 32 + kp];
    }
#pragma unroll
    for (int i = 0; i < 12; ++i) {
      int idx = t + 512 * i;
      int row = idx >> 5, kp = idx & 31;
      int gate = row >> 6, cl = row & 63;
      gU[(gate * 64 + cl) * 36 + kp] = pkbf(wv[i].x, wv[i].y);
    }
#pragma unroll
    for (int i = 0; i < 12; ++i) {
      int idx = t + 512 * i;
      int row = idx >> 5, kp = idx & 31;
      wv[i] = whh2[row * 32 + kp];
    }
#pragma unroll
    for (int i = 0; i < 12; ++i) {
      int idx = t + 512 * i;
      int row = idx >> 5, kp = idx & 31;
      int gate = row >> 6, cl = row & 63;
      gU[((gate + 3) * 64 + cl) * 36 + kp] = pkbf(wv[i].x, wv[i].y);
    }
  }

  const int w = t >> 6, l = t & 63;
  const int m = l & 15, g = l >> 4;
  const int rowA = n0 + w * 16 + m;      // A-operand row for this lane

  // ---- fc1 phase ----
  bf16x8 af[3];
#pragma unroll
  for (int ks = 0; ks < 3; ++ks) {
    const float4* p = (const float4*)(in + (size_t)rowA * 96 + ks * 32 + g * 8);
    float4 a = p[0], b = p[1];
    union { unsigned u[4]; bf16x8 h; } tw;
    tw.u[0] = pkbf(a.x, a.y); tw.u[1] = pkbf(a.z, a.w);
    tw.u[2] = pkbf(b.x, b.y); tw.u[3] = pkbf(b.z, b.w);
    af[ks] = tw.h;
  }
  {
    f32x4 accx[4];
#pragma unroll
    for (int ct = 0; ct < 4; ++ct) accx[ct] = (f32x4){0.f, 0.f, 0.f, 0.f};
#pragma unroll
    for (int ct = 0; ct < 4; ++ct)
#pragma unroll
      for (int ks = 0; ks < 3; ++ks) {
        const float4* p = (const float4*)(fc1w + (ct * 16 + m) * 96 + ks * 32 + g * 8);
        float4 a = p[0], b = p[1];
        union { unsigned u[4]; bf16x8 h; } tw;
        tw.u[0] = pkbf(a.x, a.y); tw.u[1] = pkbf(a.z, a.w);
        tw.u[2] = pkbf(b.x, b.y); tw.u[3] = pkbf(b.z, b.w);
        accx[ct] = __builtin_amdgcn_mfma_f32_16x16x32_bf16(af[ks], tw.h, accx[ct], 0, 0, 0);
      }
#pragma unroll
    for (int ct = 0; ct < 4; ++ct) {
      int c = ct * 16 + m;
      float bc = fc1b[c];
#pragma unroll
      for (int reg = 0; reg < 4; ++reg) {
        int nl = w * 16 + g * 4 + reg;
        float v = fmaxf(accx[ct][reg] + bc, 0.f);
        xS[nl * 72 + c] = (short)((__float_as_uint(v) + 0x8000u) >> 16);
      }
    }
  }
  __syncthreads();   // xS ready + gU ready

  // ---- GRU phase ----
  bf16x8 ax[2], ah[2];
#pragma unroll
  for (int ks = 0; ks < 2; ++ks) {
    ax[ks] = *(const bf16x8*)(xS + (w * 16 + m) * 72 + ks * 32 + g * 8);
    const float4* p = (const float4*)(hprev + (size_t)rowA * 64 + ks * 32 + g * 8);
    float4 a = p[0], b = p[1];
    union { unsigned u[4]; bf16x8 h; } tw;
    tw.u[0] = pkbf(a.x, a.y); tw.u[1] = pkbf(a.z, a.w);
    tw.u[2] = pkbf(b.x, b.y); tw.u[3] = pkbf(b.z, b.w);
    ah[ks] = tw.h;
  }
  const short* gS = (const short*)gU;
  float hc[4][4];
#pragma unroll 1
  for (int ct = 0; ct < 4; ++ct) {
    f32x4 a_ir = (f32x4){0.f,0.f,0.f,0.f}, a_iz = (f32x4){0.f,0.f,0.f,0.f},
          a_in = (f32x4){0.f,0.f,0.f,0.f}, a_hr = (f32x4){0.f,0.f,0.f,0.f},
          a_hz = (f32x4){0.f,0.f,0.f,0.f}, a_hn = (f32x4){0.f,0.f,0.f,0.f};
    int crow = ct * 16 + m;
#pragma unroll
    for (int ks = 0; ks < 2; ++ks) {
      bf16x8 b0 = *(const bf16x8*)(gS + (0 * 64 + crow) * 72 + ks * 32 + g * 8);
      bf16x8 b1 = *(const bf16x8*)(gS + (1 * 64 + crow) * 72 + ks * 32 + g * 8);
      bf16x8 b2 = *(const bf16x8*)(gS + (2 * 64 + crow) * 72 + ks * 32 + g * 8);
      bf16x8 b3 = *(const bf16x8*)(gS + (3 * 64 + crow) * 72 + ks * 32 + g * 8);
      bf16x8 b4 = *(const bf16x8*)(gS + (4 * 64 + crow) * 72 + ks * 32 + g * 8);
      bf16x8 b5 = *(const bf16x8*)(gS + (5 * 64 + crow) * 72 + ks * 32 + g * 8);
      a_ir = __builtin_amdgcn_mfma_f32_16x16x32_bf16(ax[ks], b0, a_ir, 0, 0, 0);
      a_iz = __builtin_amdgcn_mfma_f32_16x16x32_bf16(ax[ks], b1, a_iz, 0, 0, 0);
      a_in = __builtin_amdgcn_mfma_f32_16x16x32_bf16(ax[ks], b2, a_in, 0, 0, 0);
      a_hr = __builtin_amdgcn_mfma_f32_16x16x32_bf16(ah[ks], b3, a_hr, 0, 0, 0);
      a_hz = __builtin_amdgcn_mfma_f32_16x16x32_bf16(ah[ks], b4, a_hz, 0, 0, 0);
      a_hn = __builtin_amdgcn_mfma_f32_16x16x32_bf16(ah[ks], b5, a_hn, 0, 0, 0);
    }
    float bir = bih[crow], biz = bih[64 + crow], bin = bih[128 + crow];
    float bhr = bhh[crow], bhz = bhh[64 + crow], bhn = bhh[128 + crow];
#pragma unroll
    for (int reg = 0; reg < 4; ++reg) {
      int nl = w * 16 + g * 4 + reg;
      float hv = hprev[(size_t)(n0 + nl) * 64 + crow];
      float r  = sigmoidf_(a_ir[reg] + bir + a_hr[reg] + bhr);
      float z  = sigmoidf_(a_iz[reg] + biz + a_hz[reg] + bhz);
      float nn = tanhf(a_in[reg] + bin + r * (a_hn[reg] + bhn));
      hc[ct][reg] = (1.f - z) * nn + z * hv;
    }
  }
  __syncthreads();   // all waves done reading gU before trF overlay
#pragma unroll
  for (int ct = 0; ct < 4; ++ct)
#pragma unroll
    for (int reg = 0; reg < 4; ++reg)
      trF[(ct * 16 + m) * 133 + w * 16 + g * 4 + reg] = hc[ct][reg];
  __syncthreads();
#pragma unroll
  for (int i = 0; i < 16; ++i) {
    int idx = t + 512 * i;
    int nl = idx & 127, cl = idx >> 7;
    hT[(size_t)cl * NROW + n0 + nl] = trF[cl * 133 + nl];
  }
#pragma unroll
  for (int i = 0; i < 16; ++i) {
    int idx = t + 512 * i;
    int c = idx & 63, nl = idx >> 6;
    hout[(size_t)(n0 + nl) * 64 + c] = trF[c * 133 + nl];
  }
}

// K3 (MFMA): 96-channel fused head GEMM (fc2 16 + qk 16 + ew1 64), K=64.
// Staging de-serialized: batched h loads; copy-rows pass + dedicated qk pass.
__global__ __launch_bounds__(256) void k_heads(const float* __restrict__ hT,
    const float* __restrict__ fc2w, const float* __restrict__ fc2b,
    const float* __restrict__ wqw, const float* __restrict__ wkw,
    const float* __restrict__ ew1, const float* __restrict__ eb1,
    float* __restrict__ qT, float* __restrict__ qkT, float* __restrict__ z1T,
    float* __restrict__ part) {
  __shared__ char smem[36864];
  const int t = threadIdx.x;
  const int n0 = blockIdx.x * 128;
  unsigned* hU = (unsigned*)smem;                 // [128][36]
  unsigned* wU = (unsigned*)(smem + 18432);       // [96][36]
  float* sp1 = (float*)(smem + 18432 + 13824);    // [4][64]
  float* sp2 = sp1 + 256;                         // [4][64]
  const float qs = 0.17677669529663687f;          // 1/sqrt(32)

  {  // h staging: batched loads
    float va[16], vb[16];
#pragma unroll
    for (int i = 0; i < 16; ++i) {
      int idx = t + 256 * i;
      int nl = idx & 127, kp = idx >> 7;
      va[i] = hT[(size_t)(2 * kp) * NROW + n0 + nl];
      vb[i] = hT[(size_t)(2 * kp + 1) * NROW + n0 + nl];
    }
#pragma unroll
    for (int i = 0; i < 16; ++i) {
      int idx = t + 256 * i;
      int nl = idx & 127, kp = idx >> 7;
      hU[nl * 36 + kp] = pkbf(va[i], vb[i]);
    }
  }
  {  // weight copies: fc2 (wU rows 0..15) + ew1 (wU rows 32..95)
    float2 wv[10];
#pragma unroll
    for (int i = 0; i < 10; ++i) {
      int idx = t + 256 * i;            // 0..2559
      int kp = idx & 31, cl = idx >> 5; // 0..79
      const float* src = (cl < 16) ? (fc2w + cl * 64) : (ew1 + (cl - 16) * 64);
      wv[i] = *(const float2*)(src + 2 * kp);
    }
#pragma unroll
    for (int i = 0; i < 10; ++i) {
      int idx = t + 256 * i;
      int kp = idx & 31, cl = idx >> 5;
      int dst = (cl < 16) ? cl : (cl + 16);
      wU[dst * 36 + kp] = pkbf(wv[i].x, wv[i].y);
    }
  }
  {  // qk rows (wU rows 16..31): qs * Wk^T Wq, inner loop unrolled
    int kp = t & 31, ll = t >> 5;   // ll 0..7; rows ll, ll+8
#pragma unroll
    for (int h = 0; h < 2; ++h) {
      int row = ll + 8 * h;
      float s0 = 0.f, s1 = 0.f;
#pragma unroll
      for (int a = 0; a < 32; ++a) {
        float wk = wkw[a * 16 + row];
        s0 = fmaf(wk, wqw[a * 64 + 2 * kp], s0);
        s1 = fmaf(wk, wqw[a * 64 + 2 * kp + 1], s1);
      }
      wU[(16 + row) * 36 + kp] = pkbf(s0 * qs, s1 * qs);
    }
  }
  __syncthreads();

  const int w = t >> 6, l = t & 63;
  const int m = l & 15, g = l >> 4;
  const short* sH = (const short*)hU;
  const short* sW = (const short*)wU;

  bf16x8 af[2][2];
#pragma unroll
  for (int mt = 0; mt < 2; ++mt)
#pragma unroll
    for (int ks = 0; ks < 2; ++ks)
      af[mt][ks] = *(const bf16x8*)(sH + (w * 32 + mt * 16 + m) * 72 + ks * 32 + g * 8);

  f32x4 acc[2][6];
#pragma unroll
  for (int mt = 0; mt < 2; ++mt)
#pragma unroll
    for (int ct = 0; ct < 6; ++ct) acc[mt][ct] = (f32x4){0.f, 0.f, 0.f, 0.f};
#pragma unroll
  for (int ct = 0; ct < 6; ++ct)
#pragma unroll
    for (int ks = 0; ks < 2; ++ks) {
      bf16x8 bw = *(const bf16x8*)(sW + (ct * 16 + m) * 72 + ks * 32 + g * 8);
#pragma unroll
      for (int mt = 0; mt < 2; ++mt)
        acc[mt][ct] = __builtin_amdgcn_mfma_f32_16x16x32_bf16(af[mt][ks], bw, acc[mt][ct], 0, 0, 0);
    }

  float s1[4], s2[4];
#pragma unroll
  for (int zt = 0; zt < 4; ++zt) { s1[zt] = 0.f; s2[zt] = 0.f; }
#pragma unroll
  for (int mt = 0; mt < 2; ++mt) {
    int nb = n0 + w * 32 + mt * 16 + g * 4;
    {  // q head: c = m
      float bc = fc2b[m];
      f32x4 v;
#pragma unroll
      for (int reg = 0; reg < 4; ++reg) v[reg] = acc[mt][0][reg] + bc;
      *(f32x4*)(qT + (size_t)m * NROW + nb) = v;
    }
    // qk head: l' = m, no bias
    *(f32x4*)(qkT + (size_t)m * NROW + nb) = acc[mt][1];
#pragma unroll
    for (int ct = 2; ct < 6; ++ct) {  // z1 head: z = (ct-2)*16 + m
      int z = (ct - 2) * 16 + m;
      float bc = eb1[z];
      f32x4 v;
#pragma unroll
      for (int reg = 0; reg < 4; ++reg) {
        float zv = acc[mt][ct][reg] + bc;
        v[reg] = zv;
        s1[ct - 2] += zv;
        s2[ct - 2] = fmaf(zv, zv, s2[ct - 2]);
      }
      *(f32x4*)(z1T + (size_t)z * NROW + nb) = v;
    }
  }
#pragma unroll
  for (int zt = 0; zt < 4; ++zt) {
    s1[zt] += __shfl_down(s1[zt], 16, 64);
    s1[zt] += __shfl_down(s1[zt], 32, 64);
    s2[zt] += __shfl_down(s2[zt], 16, 64);
    s2[zt] += __shfl_down(s2[zt], 32, 64);
  }
  if (l < 16) {
#pragma unroll
    for (int zt = 0; zt < 4; ++zt) {
      sp1[w * 64 + zt * 16 + m] = s1[zt];
      sp2[w * 64 + zt * 16 + m] = s2[zt];
    }
  }
  __syncthreads();
  if (t < 64) {
    float a1 = sp1[t] + sp1[64 + t] + sp1[128 + t] + sp1[192 + t];
    float a2 = sp2[t] + sp2[64 + t] + sp2[128 + t] + sp2[192 + t];
    part[(size_t)blockIdx.x * 128 + t] = a1;
    part[(size_t)blockIdx.x * 128 + 64 + t] = a2;
  }
}

// K4: block 0 = BN stats (4-way sliced); blocks 1..64 = pack ew2 f32 -> bf16
// (16 rows of 64 each) into ew2b [1024][32] u32 for the fused k_msg GEMM.
__global__ __launch_bounds__(256) void k_bnstat(const float* __restrict__ part,
    const float* __restrict__ bng, const float* __restrict__ bnb,
    const float* __restrict__ ew2,
    float* __restrict__ stat, unsigned* __restrict__ ew2b) {
  if (blockIdx.x == 0) {
    __shared__ float red[512];
    const int t = threadIdx.x;        // 256
    const int c = t & 63, q = t >> 6; // q 0..3
    float s1 = 0.f, s2 = 0.f;
#pragma unroll 4
    for (int b = q; b < 256; b += 4) {
      s1 += part[(size_t)b * 128 + c];
      s2 += part[(size_t)b * 128 + 64 + c];
    }
    red[q * 64 + c] = s1;
    red[256 + q * 64 + c] = s2;
    __syncthreads();
    if (t < 64) {
      float a1 = red[t] + red[64 + t] + red[128 + t] + red[192 + t];
      float a2 = red[256 + t] + red[320 + t] + red[384 + t] + red[448 + t];
      float mean = a1 * (1.f / NROW);
      float var = a2 * (1.f / NROW) - mean * mean;
      float rstd = rsqrtf(var + 1e-5f);
      float sc = bng[t] * rstd;
      stat[t] = sc;
      stat[64 + t] = bnb[t] - mean * sc;
    }
  } else {
    const int rb = blockIdx.x - 1;    // 0..63 -> rows rb*16 .. rb*16+15
    const int t = threadIdx.x;
#pragma unroll
    for (int it = 0; it < 2; ++it) {
      int id2 = t + 256 * it;          // 0..511 col-pairs
      int r = rb * 16 + (id2 >> 5);    // row
      int cp = id2 & 31;               // col-pair 0..31
      float2 v = *(const float2*)(ew2 + (size_t)r * 64 + 2 * cp);
      ew2b[(size_t)r * 32 + cp] = pkbf(v.x, v.y);
    }
  }
}

// K7 (fused, v2): one block per b, 512 threads / 8 waves. Latent GEMM in-block
// into LDS latB (9-u32 rows), logits+softmax, msg main loop 8 iters/wave.
// LDS 80256 B -> 2 blocks/CU (16 waves/CU). QKL overlays MT (lifetimes disjoint).
constexpr int LATB_OFF = 0;        // [1024][18] bf16, 36B rows (r = i*32+j)
constexpr int H3B_OFF  = 36864;    // [32][72] bf16, 144B rows
constexpr int W1H_OFF  = 41472;    // [64][72] bf16
constexpr int W1L_OFF  = 50688;    // [64][20] bf16
constexpr int W2P_OFF  = 53248;    // [16][72] bf16 (pi-permuted c)
constexpr int ALL_OFF  = 55552;    // [32][33] f32 alpha
constexpr int MT_OFF   = 59776;    // 8 waves x 2560B private transpose buf; xz+QKL overlays pre-main-loop
constexpr int QKL_OFF  = MT_OFF + 4608;   // [32][20] f32 qk (overlay; dead before wb writes)
__global__ __launch_bounds__(512, 1) void k_msg(
    const unsigned* __restrict__ ew2b, const float* __restrict__ stat,
    const float* __restrict__ z1T, const float* __restrict__ eb2,
    const float* __restrict__ eps,
    const float* __restrict__ qkT,
    const float* __restrict__ qT, const float* __restrict__ hrow,
    const float* __restrict__ w1, const float* __restrict__ b1,
    const float* __restrict__ w2, const float* __restrict__ b2,
    float* __restrict__ out) {
  __shared__ char smem[80256];
  const int t = threadIdx.x;
  const int b = blockIdx.x;
  const int b32 = b * 32;
  unsigned* latB_dw = (unsigned*)(smem + LATB_OFF);

  const int w = t >> 6, l = t & 63;
  const int m = l & 15, g = l >> 4;

  // ---- staging (512 threads) ----
  {  // xz: z1 slice [32 rows][64 k] -> BN+lrelu -> bf16 @ MT_OFF overlay
    short* xz = (short*)(smem + MT_OFF);
    float zv[4];
#pragma unroll
    for (int it = 0; it < 4; ++it) {
      int idx = t + 512 * it;          // 0..2047
      int i = idx & 31, c = idx >> 5;  // row 0..31, col 0..63
      zv[it] = z1T[(size_t)c * NROW + b32 + i];
    }
#pragma unroll
    for (int it = 0; it < 4; ++it) {
      int idx = t + 512 * it;
      int i = idx & 31, c = idx >> 5;
      float v = lrelu_(fmaf(stat[c], zv[it], stat[64 + c]));
      xz[i * 72 + c] = (short)((__float_as_uint(v) + 0x8000u) >> 16);
    }
  }
  {  // qkL[i][l] from qkT (512 entries = 1/thread)
    float* qkL = (float*)(smem + QKL_OFF);
    int i = t & 31, ll = t >> 5;       // ll 0..15
    qkL[i * 20 + ll] = qkT[(size_t)ll * NROW + b32 + i];
  }
  {  // h3B[j][k] bf16 from row-major h
    int cp = t & 31, jbase = t >> 5;   // jbase 0..15
    const float2* h2 = (const float2*)hrow;
    float2 hv[2];
#pragma unroll
    for (int it = 0; it < 2; ++it)
      hv[it] = h2[((size_t)(b32 + jbase + 16 * it) * 64 + 2 * cp) >> 1];
    unsigned* dst = (unsigned*)(smem + H3B_OFF);
#pragma unroll
    for (int it = 0; it < 2; ++it)
      dst[(jbase + 16 * it) * 36 + cp] = pkbf(hv[it].x, hv[it].y);
  }
  {  // w1hL[c][k] (k<64)
    int kp = t & 31, cb = t >> 5;      // cb 0..15
    const float2* w12 = (const float2*)w1;
    float2 wv[4];
#pragma unroll
    for (int it = 0; it < 4; ++it)
      wv[it] = w12[((cb + 16 * it) * 80 + 2 * kp) >> 1];
    unsigned* dst = (unsigned*)(smem + W1H_OFF);
#pragma unroll
    for (int it = 0; it < 4; ++it)
      dst[(cb + 16 * it) * 36 + kp] = pkbf(wv[it].x, wv[it].y);
  }
  {  // w1latL[c][l] (512 entries = 1/thread)
    int lp = t & 7, cc = t >> 3;       // cc 0..63
    const float2* w12 = (const float2*)w1;
    float2 wv = w12[(cc * 80 + 64 + 2 * lp) >> 1];
    unsigned* dst = (unsigned*)(smem + W1L_OFF);
    dst[cc * 10 + lp] = pkbf(wv.x, wv.y);
  }
  {  // w2P[nn][p] = w2[nn][c(p)] (512 entries = 1/thread)
    int pp = t & 31, nn = t >> 5;      // nn 0..15
    const float2* w22 = (const float2*)w2;
    int p = 2 * pp;
    int c = ((p >> 2) & 3) * 16 + (p >> 4) * 4 + (p & 3);
    float2 wv0 = w22[(nn * 64 + c) >> 1];
    unsigned* dst = (unsigned*)(smem + W2P_OFF);
    dst[nn * 36 + pp] = pkbf(wv0.x, wv0.y);
  }
  __syncthreads();   // all staging (incl. xz, QKL) visible

  // ---- latent GEMM: lat[32][512] -> latB (LDS), wave w owns j-tiles w*4..w*4+3 ----
  {
    const short* xzS = (const short*)(smem + MT_OFF);
    bf16x8 afz[2][2];
#pragma unroll
    for (int mt = 0; mt < 2; ++mt)
#pragma unroll
      for (int ks = 0; ks < 2; ++ks)
        afz[mt][ks] = *(const bf16x8*)(xzS + (mt * 16 + m) * 72 + ks * 32 + g * 8);
    const uint4e* w4 = (const uint4e*)ew2b;
    const float stdfloor = 0.04472135955f;   // sqrt(0.002)
#pragma unroll 2
    for (int ci8 = 0; ci8 < 4; ++ci8) {
      int ci = w * 4 + ci8;                  // j-tile 0..31
      int c = ci * 16 + m;                   // latent column
      union { uint4e u; bf16x8 h; } bmu[2], blv[2];
#pragma unroll
      for (int ks = 0; ks < 2; ++ks) {
        bmu[ks].u = w4[(size_t)(ci * 16 + m) * 8 + ks * 4 + g];
        blv[ks].u = w4[(size_t)(512 + ci * 16 + m) * 8 + ks * 4 + g];
      }
      float ep[2][4];
#pragma unroll
      for (int mt = 0; mt < 2; ++mt)
#pragma unroll
        for (int reg = 0; reg < 4; ++reg)
          ep[mt][reg] = eps[(size_t)(b32 + mt * 16 + g * 4 + reg) * 512 + c];
      f32x4 accm[2], accl[2];
#pragma unroll
      for (int mt = 0; mt < 2; ++mt) {
        accm[mt] = (f32x4){0.f, 0.f, 0.f, 0.f};
        accl[mt] = (f32x4){0.f, 0.f, 0.f, 0.f};
      }
#pragma unroll
      for (int ks = 0; ks < 2; ++ks)
#pragma unroll
        for (int mt = 0; mt < 2; ++mt) {
          accm[mt] = __builtin_amdgcn_mfma_f32_16x16x32_bf16(afz[mt][ks], bmu[ks].h, accm[mt], 0, 0, 0);
          accl[mt] = __builtin_amdgcn_mfma_f32_16x16x32_bf16(afz[mt][ks], blv[ks].h, accl[mt], 0, 0, 0);
        }
      float ebm = eb2[c], ebl = eb2[DH + c];
#pragma unroll
      for (int mt = 0; mt < 2; ++mt)
#pragma unroll
        for (int reg = 0; reg < 4; ++reg) {
          float mu = accm[mt][reg] + ebm;
          float lv = accl[mt][reg] + ebl;
          float sd = fmaxf(__expf(0.5f * lv), stdfloor);
          float lat = fmaf(sd, ep[mt][reg], mu);
          float lat2 = __shfl_xor(lat, 1, 64);
          if (!(m & 1)) {
            int i = mt * 16 + g * 4 + reg;
            latB_dw[(i * 32 + ci) * 9 + (m >> 1)] = pkbf(lat, lat2);
          }
        }
    }
  }
  __syncthreads();   // latB complete before logits

  // ---- logits + softmax -> alL (reads latB + qkL) ----
  {
    const float* qkL = (const float*)(smem + QKL_OFF);
    float* alL = (float*)(smem + ALL_OFF);
#pragma unroll 1
    for (int p = 0; p < 2; ++p) {
      int i = (t >> 5) + 16 * p;
      int j = t & 31;
      const unsigned* lr = latB_dw + (i * 32 + j) * 9;
      float acc = 0.f;
#pragma unroll
      for (int d = 0; d < 8; ++d) {
        unsigned u = lr[d];
        float lo = __uint_as_float(u << 16);
        float hi = __uint_as_float(u & 0xffff0000u);
        acc = fmaf(lo, qkL[i * 20 + 2 * d], acc);
        acc = fmaf(hi, qkL[i * 20 + 2 * d + 1], acc);
      }
      if (j == i) acc = -1e9f;
      float mx = acc;
#pragma unroll
      for (int msk = 16; msk > 0; msk >>= 1) mx = fmaxf(mx, __shfl_xor(mx, msk, 32));
      float e = __expf(acc - mx);
      float s = e;
#pragma unroll
      for (int msk = 16; msk > 0; msk >>= 1) s += __shfl_xor(s, msk, 32);
      alL[i * 33 + j] = e / s;
    }
  }

  const int n15 = l & 15, q = l >> 4;
  const int jh = w & 1, ibase = (w >> 1) * 8;
  const bool kact = (q < 2);

  // ---- phase 1: hp[ct][reg] for (c = ct*16+q*4+reg, j = jh*16+n15) ----
  f32x4 hp[4];
#pragma unroll
  for (int ct = 0; ct < 4; ++ct) hp[ct] = (f32x4){0.f, 0.f, 0.f, 0.f};
#pragma unroll
  for (int ct = 0; ct < 4; ++ct)
#pragma unroll
    for (int ks = 0; ks < 2; ++ks) {
      bf16x8 aF = *(const bf16x8*)(smem + W1H_OFF + (ct * 16 + n15) * 144 + ks * 64 + q * 16);
      bf16x8 bF = *(const bf16x8*)(smem + H3B_OFF + (jh * 16 + n15) * 144 + ks * 64 + q * 16);
      hp[ct] = __builtin_amdgcn_mfma_f32_16x16x32_bf16(aF, bF, hp[ct], 0, 0, 0);
    }
#pragma unroll
  for (int ct = 0; ct < 4; ++ct)
#pragma unroll
    for (int reg = 0; reg < 4; ++reg)
      hp[ct][reg] += b1[ct * 16 + q * 4 + reg];

  // hoisted fragments
  bf16x8 aL[4];
#pragma unroll
  for (int ct = 0; ct < 4; ++ct) {
    union { unsigned u[4]; bf16x8 h; } tmp;
    tmp.u[0] = tmp.u[1] = tmp.u[2] = tmp.u[3] = 0u;
    if (kact) {
      const unsigned* p = (const unsigned*)(smem + W1L_OFF) + (ct * 16 + n15) * 10 + q * 4;
      uint2e d0 = *(const uint2e*)p;
      uint2e d1 = *(const uint2e*)(p + 2);
      tmp.u[0] = d0.x; tmp.u[1] = d0.y; tmp.u[2] = d1.x; tmp.u[3] = d1.y;
    }
    aL[ct] = tmp.h;
  }
  bf16x8 w2F[2];
#pragma unroll
  for (int ks = 0; ks < 2; ++ks)
    w2F[ks] = *(const bf16x8*)(smem + W2P_OFF + n15 * 144 + ks * 64 + q * 16);
  float b2v[4];
#pragma unroll
  for (int reg = 0; reg < 4; ++reg) b2v[reg] = b2[q * 4 + reg];

  __syncthreads();  // alL complete; xz+QKL dead from here (wb overlays them)

  // ---- main i loop (8 iterations/wave) ----
  float agg[4] = {0.f, 0.f, 0.f, 0.f};
  char* wb = smem + MT_OFF + w * 2560;
  const float* alLf = (const float*)(smem + ALL_OFF);
#pragma unroll 1
  for (int it = 0; it < 8; ++it) {
    int ii = ibase + it;
    int r = ii * 32 + jh * 16 + n15;
    union { unsigned u[4]; bf16x8 h; } latF;
    latF.u[0] = latF.u[1] = latF.u[2] = latF.u[3] = 0u;
    if (kact) {
      const unsigned* p = latB_dw + r * 9 + q * 4;
      latF.u[0] = p[0]; latF.u[1] = p[1]; latF.u[2] = p[2]; latF.u[3] = p[3];
    }
    f32x4 acc[4];
#pragma unroll
    for (int ct = 0; ct < 4; ++ct) {
      acc[ct] = (f32x4){0.f, 0.f, 0.f, 0.f};
      acc[ct] = __builtin_amdgcn_mfma_f32_16x16x32_bf16(aL[ct], latF.h, acc[ct], 0, 0, 0);
    }
    // lrelu + pack + pi-transpose write (per-wave private buffer, no barrier)
#pragma unroll
    for (int h = 0; h < 2; ++h) {
      float m0[4], m1[4];
#pragma unroll
      for (int reg = 0; reg < 4; ++reg) {
        float v0 = acc[2 * h][reg] + hp[2 * h][reg];
        float v1 = acc[2 * h + 1][reg] + hp[2 * h + 1][reg];
        m0[reg] = fmaxf(v0, 0.01f * v0);
        m1[reg] = fmaxf(v1, 0.01f * v1);
      }
      uint4e pk4;
      pk4.x = pkbf(m0[0], m0[1]); pk4.y = pkbf(m0[2], m0[3]);
      pk4.z = pkbf(m1[0], m1[1]); pk4.w = pkbf(m1[2], m1[3]);
      int qp = (2 * q + h) & 3;
      *(uint4e*)(wb + (q >> 1) * 1280 + n15 * 80 + qp * 16) = pk4;
    }
    // phase 3
    f32x4 msg = (f32x4){0.f, 0.f, 0.f, 0.f};
#pragma unroll
    for (int ks = 0; ks < 2; ++ks) {
      bf16x8 mF = *(const bf16x8*)(wb + ks * 1280 + n15 * 80 + q * 16);
      msg = __builtin_amdgcn_mfma_f32_16x16x32_bf16(w2F[ks], mF, msg, 0, 0, 0);
    }
    float aw = alLf[ii * 33 + jh * 16 + n15];
#pragma unroll
    for (int reg = 0; reg < 4; ++reg)
      agg[reg] = fmaf(aw, msg[reg] + b2v[reg], agg[reg]);
  }
  // park agg in own wave buffer
  {
    f32x4 av; av[0] = agg[0]; av[1] = agg[1]; av[2] = agg[2]; av[3] = agg[3];
    *(f32x4*)(wb + n15 * 80 + q * 16) = av;
  }
  __syncthreads();
  // combine 4 i-quarters (waves jh2, jh2+2, jh2+4, jh2+6) and add q head
  {
    int jg = t >> 4, nn = t & 15;
    int jh2 = jg >> 4, jl = jg & 15;
    float s = qT[(size_t)nn * NROW + b32 + jg];
#pragma unroll
    for (int k = 0; k < 4; ++k)
      s += *(const float*)(smem + MT_OFF + (jh2 + 2 * k) * 2560 + jl * 80 + nn * 4);
    out[(size_t)b * 512 + t] = s;
  }
}

}  // namespace

extern "C" void kernel_launch(void* const* d_in, const int* in_sizes, int n_in,
                              void* d_out, int out_size, void* d_ws, size_t ws_size,
                              hipStream_t stream) {
  (void)in_sizes; (void)n_in; (void)out_size; (void)ws_size;
  const float* inputs = (const float*)d_in[0];
  const float* hidden = (const float*)d_in[1];
  const float* eps    = (const float*)d_in[2];
  const float* fc1w   = (const float*)d_in[3];
  const float* fc1b   = (const float*)d_in[4];
  const float* wih    = (const float*)d_in[5];
  const float* whh    = (const float*)d_in[6];
  const float* bih    = (const float*)d_in[7];
  const float* bhh    = (const float*)d_in[8];
  const float* fc2w   = (const float*)d_in[9];
  const float* fc2b   = (const float*)d_in[10];
  const float* ew1    = (const float*)d_in[11];
  const float* eb1    = (const float*)d_in[12];
  const float* bng    = (const float*)d_in[13];
  const float* bnb    = (const float*)d_in[14];
  const float* ew2    = (const float*)d_in[15];
  const float* eb2    = (const float*)d_in[16];
  const float* w1     = (const float*)d_in[17];
  const float* b1     = (const float*)d_in[18];
  const float* w2     = (const float*)d_in[19];
  const float* b2     = (const float*)d_in[20];
  const float* wqw    = (const float*)d_in[21];
  const float* wkw    = (const float*)d_in[23];

  float* ws = (float*)d_ws;
  float* hT     = ws;                 // 2097152
  float* qT     = ws + 2097152;       // 524288
  float* qkT    = ws + 2621440;       // 524288
  float* z1T    = ws + 3670016;       // 2097152
  float* part   = ws + 5767168;       // 32768 used
  float* stat   = ws + 5832704;       // 128
  unsigned* ew2b = (unsigned*)(ws + 5832832);  // [1024][32] u32 (bf16-packed ew2)

  float* out_q = (float*)d_out;             // 32768 x 16
  float* out_h = (float*)d_out + 524288;    // 32768 x 64

  hipLaunchKernelGGL(k_fgru, dim3(256), dim3(512), 0, stream,
                     inputs, hidden, fc1w, fc1b, wih, whh, bih, bhh, hT, out_h);
  hipLaunchKernelGGL(k_heads, dim3(256), dim3(256), 0, stream,
                     hT, fc2w, fc2b, wqw, wkw, ew1, eb1, qT, qkT, z1T, part);
  hipLaunchKernelGGL(k_bnstat, dim3(65), dim3(256), 0, stream, part, bng, bnb, ew2, stat, ew2b);
  hipLaunchKernelGGL(k_msg, dim3(1024), dim3(512), 0, stream,
                     ew2b, stat, z1T, eb2, eps, qkT, qT, out_h, w1, b1, w2, b2, out_q);
}

// Round 9
// 211.765 us; speedup vs baseline: 1.2128x; 1.0737x over previous
//
#include <hip/hip_runtime.h>
#include <math.h>

namespace {

constexpr int NROW = 32768;   // BS*A rows
constexpr int HDIM = 64;
constexpr int DH   = 512;     // latent half-dim

typedef __attribute__((ext_vector_type(8))) short bf16x8;
typedef __attribute__((ext_vector_type(4))) float f32x4;
typedef __attribute__((ext_vector_type(4))) unsigned uint4e;
typedef __attribute__((ext_vector_type(2))) unsigned uint2e;

__device__ __forceinline__ float sigmoidf_(float x) { return 1.f / (1.f + __expf(-x)); }
__device__ __forceinline__ float lrelu_(float x) { return x > 0.f ? x : 0.01f * x; }
// fast pack: round-half-up bf16 pair (a -> low16, b -> high16)
__device__ __forceinline__ unsigned pkbf(float a, float b) {
  unsigned ua = __float_as_uint(a) + 0x8000u;
  unsigned ub = __float_as_uint(b) + 0x8000u;
  return __builtin_amdgcn_perm(ub, ua, 0x07060302);
}

// K1+K2+K3 fused: fc1 -> GRU -> head GEMM (fc2/qk/ew1) in one kernel.
// 256 blocks x 512 threads, 8 waves x 16 rows. h never round-trips through HBM:
// hc regs -> xS (bf16, head A-frags) + trF (f32, hout transpose). hT eliminated.
__global__ __launch_bounds__(512, 1) void k_fgru(
    const float* __restrict__ in,      // [N][96]
    const float* __restrict__ hprev,   // [N][64]
    const float* __restrict__ fc1w, const float* __restrict__ fc1b,
    const float* __restrict__ wih, const float* __restrict__ whh,
    const float* __restrict__ bih, const float* __restrict__ bhh,
    const float* __restrict__ fc2w, const float* __restrict__ fc2b,
    const float* __restrict__ wqw, const float* __restrict__ wkw,
    const float* __restrict__ ew1, const float* __restrict__ eb1,
    float* __restrict__ qT, float* __restrict__ qkT, float* __restrict__ z1T,
    float* __restrict__ part, float* __restrict__ hout) {
  __shared__ char smem[91648];
  const int t = threadIdx.x;
  const int n0 = blockIdx.x * 128;
  short*    xS = (short*)smem;                 // [128][72] shorts (x, then h bf16)
  unsigned* gU = (unsigned*)(smem + 18432);    // [6][64][36]
  float*    trF = (float*)(smem + 18432);      // [64][133] f32, overlays gU after GRU
  unsigned* wU = (unsigned*)(smem + 73728);    // [96][36] head weights (fc2/qk/ew1)
  float*    sp1 = (float*)(smem + 87552);      // [8][64]
  float*    sp2 = (float*)(smem + 89600);      // [8][64]
  const float qs = 0.17677669529663687f;       // 1/sqrt(32)

  const float2* wih2 = (const float2*)wih;
  const float2* whh2 = (const float2*)whh;
  {  // gate weight staging: batched loads, then packs
    float2 wv[12];
#pragma unroll
    for (int i = 0; i < 12; ++i) {
      int idx = t + 512 * i;
      int row = idx >> 5, kp = idx & 31;
      wv[i] = wih2[row * 32 + kp];
    }
#pragma unroll
    for (int i = 0; i < 12; ++i) {
      int idx = t + 512 * i;
      int row = idx >> 5, kp = idx & 31;
      int gate = row >> 6, cl = row & 63;
      gU[(gate * 64 + cl) * 36 + kp] = pkbf(wv[i].x, wv[i].y);
    }
#pragma unroll
    for (int i = 0; i < 12; ++i) {
      int idx = t + 512 * i;
      int row = idx >> 5, kp = idx & 31;
      wv[i] = whh2[row * 32 + kp];
    }
#pragma unroll
    for (int i = 0; i < 12; ++i) {
      int idx = t + 512 * i;
      int row = idx >> 5, kp = idx & 31;
      int gate = row >> 6, cl = row & 63;
      gU[((gate + 3) * 64 + cl) * 36 + kp] = pkbf(wv[i].x, wv[i].y);
    }
  }
  {  // head weight copies: fc2 (wU rows 0..15) + ew1 (wU rows 32..95)
    float2 wv[5];
#pragma unroll
    for (int i = 0; i < 5; ++i) {
      int idx = t + 512 * i;            // 0..2559
      int kp = idx & 31, cl = idx >> 5; // 0..79
      const float* src = (cl < 16) ? (fc2w + cl * 64) : (ew1 + (cl - 16) * 64);
      wv[i] = *(const float2*)(src + 2 * kp);
    }
#pragma unroll
    for (int i = 0; i < 5; ++i) {
      int idx = t + 512 * i;
      int kp = idx & 31, cl = idx >> 5;
      int dst = (cl < 16) ? cl : (cl + 16);
      wU[dst * 36 + kp] = pkbf(wv[i].x, wv[i].y);
    }
  }
  {  // qk rows (wU rows 16..31): qs * Wk^T Wq, 1 row per thread
    int kp = t & 31, row = t >> 5;      // row 0..15
    float s0 = 0.f, s1 = 0.f;
#pragma unroll
    for (int a = 0; a < 32; ++a) {
      float wk = wkw[a * 16 + row];
      s0 = fmaf(wk, wqw[a * 64 + 2 * kp], s0);
      s1 = fmaf(wk, wqw[a * 64 + 2 * kp + 1], s1);
    }
    wU[(16 + row) * 36 + kp] = pkbf(s0 * qs, s1 * qs);
  }

  const int w = t >> 6, l = t & 63;
  const int m = l & 15, g = l >> 4;
  const int rowA = n0 + w * 16 + m;      // A-operand row for this lane

  // ---- fc1 phase ----
  bf16x8 af[3];
#pragma unroll
  for (int ks = 0; ks < 3; ++ks) {
    const float4* p = (const float4*)(in + (size_t)rowA * 96 + ks * 32 + g * 8);
    float4 a = p[0], b = p[1];
    union { unsigned u[4]; bf16x8 h; } tw;
    tw.u[0] = pkbf(a.x, a.y); tw.u[1] = pkbf(a.z, a.w);
    tw.u[2] = pkbf(b.x, b.y); tw.u[3] = pkbf(b.z, b.w);
    af[ks] = tw.h;
  }
  {
    f32x4 accx[4];
#pragma unroll
    for (int ct = 0; ct < 4; ++ct) accx[ct] = (f32x4){0.f, 0.f, 0.f, 0.f};
#pragma unroll
    for (int ct = 0; ct < 4; ++ct)
#pragma unroll
      for (int ks = 0; ks < 3; ++ks) {
        const float4* p = (const float4*)(fc1w + (ct * 16 + m) * 96 + ks * 32 + g * 8);
        float4 a = p[0], b = p[1];
        union { unsigned u[4]; bf16x8 h; } tw;
        tw.u[0] = pkbf(a.x, a.y); tw.u[1] = pkbf(a.z, a.w);
        tw.u[2] = pkbf(b.x, b.y); tw.u[3] = pkbf(b.z, b.w);
        accx[ct] = __builtin_amdgcn_mfma_f32_16x16x32_bf16(af[ks], tw.h, accx[ct], 0, 0, 0);
      }
#pragma unroll
    for (int ct = 0; ct < 4; ++ct) {
      int c = ct * 16 + m;
      float bc = fc1b[c];
#pragma unroll
      for (int reg = 0; reg < 4; ++reg) {
        int nl = w * 16 + g * 4 + reg;
        float v = fmaxf(accx[ct][reg] + bc, 0.f);
        xS[nl * 72 + c] = (short)((__float_as_uint(v) + 0x8000u) >> 16);
      }
    }
  }
  __syncthreads();   // xS(x) + gU + wU ready

  // ---- GRU phase ----
  bf16x8 ax[2], ah[2];
#pragma unroll
  for (int ks = 0; ks < 2; ++ks) {
    ax[ks] = *(const bf16x8*)(xS + (w * 16 + m) * 72 + ks * 32 + g * 8);
    const float4* p = (const float4*)(hprev + (size_t)rowA * 64 + ks * 32 + g * 8);
    float4 a = p[0], b = p[1];
    union { unsigned u[4]; bf16x8 h; } tw;
    tw.u[0] = pkbf(a.x, a.y); tw.u[1] = pkbf(a.z, a.w);
    tw.u[2] = pkbf(b.x, b.y); tw.u[3] = pkbf(b.z, b.w);
    ah[ks] = tw.h;
  }
  const short* gS = (const short*)gU;
  float hc[4][4];
#pragma unroll 1
  for (int ct = 0; ct < 4; ++ct) {
    f32x4 a_ir = (f32x4){0.f,0.f,0.f,0.f}, a_iz = (f32x4){0.f,0.f,0.f,0.f},
          a_in = (f32x4){0.f,0.f,0.f,0.f}, a_hr = (f32x4){0.f,0.f,0.f,0.f},
          a_hz = (f32x4){0.f,0.f,0.f,0.f}, a_hn = (f32x4){0.f,0.f,0.f,0.f};
    int crow = ct * 16 + m;
#pragma unroll
    for (int ks = 0; ks < 2; ++ks) {
      bf16x8 b0 = *(const bf16x8*)(gS + (0 * 64 + crow) * 72 + ks * 32 + g * 8);
      bf16x8 b1 = *(const bf16x8*)(gS + (1 * 64 + crow) * 72 + ks * 32 + g * 8);
      bf16x8 b2 = *(const bf16x8*)(gS + (2 * 64 + crow) * 72 + ks * 32 + g * 8);
      bf16x8 b3 = *(const bf16x8*)(gS + (3 * 64 + crow) * 72 + ks * 32 + g * 8);
      bf16x8 b4 = *(const bf16x8*)(gS + (4 * 64 + crow) * 72 + ks * 32 + g * 8);
      bf16x8 b5 = *(const bf16x8*)(gS + (5 * 64 + crow) * 72 + ks * 32 + g * 8);
      a_ir = __builtin_amdgcn_mfma_f32_16x16x32_bf16(ax[ks], b0, a_ir, 0, 0, 0);
      a_iz = __builtin_amdgcn_mfma_f32_16x16x32_bf16(ax[ks], b1, a_iz, 0, 0, 0);
      a_in = __builtin_amdgcn_mfma_f32_16x16x32_bf16(ax[ks], b2, a_in, 0, 0, 0);
      a_hr = __builtin_amdgcn_mfma_f32_16x16x32_bf16(ah[ks], b3, a_hr, 0, 0, 0);
      a_hz = __builtin_amdgcn_mfma_f32_16x16x32_bf16(ah[ks], b4, a_hz, 0, 0, 0);
      a_hn = __builtin_amdgcn_mfma_f32_16x16x32_bf16(ah[ks], b5, a_hn, 0, 0, 0);
    }
    float bir = bih[crow], biz = bih[64 + crow], bin = bih[128 + crow];
    float bhr = bhh[crow], bhz = bhh[64 + crow], bhn = bhh[128 + crow];
#pragma unroll
    for (int reg = 0; reg < 4; ++reg) {
      int nl = w * 16 + g * 4 + reg;
      float hv = hprev[(size_t)(n0 + nl) * 64 + crow];
      float r  = sigmoidf_(a_ir[reg] + bir + a_hr[reg] + bhr);
      float z  = sigmoidf_(a_iz[reg] + biz + a_hz[reg] + bhz);
      float nn = tanhf(a_in[reg] + bin + r * (a_hn[reg] + bhn));
      hc[ct][reg] = (1.f - z) * nn + z * hv;
    }
  }
  // hc -> xS as bf16 (own-wave rows only; becomes head-GEMM A operand)
#pragma unroll
  for (int ct = 0; ct < 4; ++ct)
#pragma unroll
    for (int reg = 0; reg < 4; ++reg) {
      int nl = w * 16 + g * 4 + reg;
      xS[nl * 72 + ct * 16 + m] =
          (short)((__float_as_uint(hc[ct][reg]) + 0x8000u) >> 16);
    }

  // ---- head GEMM: A = h (xS own rows), B = wU (96 outputs), K=64 ----
  bf16x8 af2[2];
#pragma unroll
  for (int ks = 0; ks < 2; ++ks)
    af2[ks] = *(const bf16x8*)(xS + (w * 16 + m) * 72 + ks * 32 + g * 8);
  const short* sW = (const short*)wU;
  f32x4 acc[6];
#pragma unroll
  for (int ct = 0; ct < 6; ++ct) acc[ct] = (f32x4){0.f, 0.f, 0.f, 0.f};
#pragma unroll
  for (int ct = 0; ct < 6; ++ct)
#pragma unroll
    for (int ks = 0; ks < 2; ++ks) {
      bf16x8 bw = *(const bf16x8*)(sW + (ct * 16 + m) * 72 + ks * 32 + g * 8);
      acc[ct] = __builtin_amdgcn_mfma_f32_16x16x32_bf16(af2[ks], bw, acc[ct], 0, 0, 0);
    }

  __syncthreads();   // all waves done reading gU -> trF overlay safe
#pragma unroll
  for (int ct = 0; ct < 4; ++ct)
#pragma unroll
    for (int reg = 0; reg < 4; ++reg)
      trF[(ct * 16 + m) * 133 + w * 16 + g * 4 + reg] = hc[ct][reg];
  __syncthreads();
#pragma unroll
  for (int i = 0; i < 16; ++i) {
    int idx = t + 512 * i;
    int c = idx & 63, nl = idx >> 6;
    hout[(size_t)(n0 + nl) * 64 + c] = trF[c * 133 + nl];
  }

  // ---- head epilogue: qT/qkT/z1T + BN partial sums ----
  float s1[4], s2[4];
#pragma unroll
  for (int zt = 0; zt < 4; ++zt) { s1[zt] = 0.f; s2[zt] = 0.f; }
  {
    int nb = n0 + w * 16 + g * 4;
    {  // q head: c = m
      float bc = fc2b[m];
      f32x4 v;
#pragma unroll
      for (int reg = 0; reg < 4; ++reg) v[reg] = acc[0][reg] + bc;
      *(f32x4*)(qT + (size_t)m * NROW + nb) = v;
    }
    // qk head: l' = m, no bias
    *(f32x4*)(qkT + (size_t)m * NROW + nb) = acc[1];
#pragma unroll
    for (int ct = 2; ct < 6; ++ct) {  // z1 head: z = (ct-2)*16 + m
      int z = (ct - 2) * 16 + m;
      float bc = eb1[z];
      f32x4 v;
#pragma unroll
      for (int reg = 0; reg < 4; ++reg) {
        float zv = acc[ct][reg] + bc;
        v[reg] = zv;
        s1[ct - 2] += zv;
        s2[ct - 2] = fmaf(zv, zv, s2[ct - 2]);
      }
      *(f32x4*)(z1T + (size_t)z * NROW + nb) = v;
    }
  }
#pragma unroll
  for (int zt = 0; zt < 4; ++zt) {
    s1[zt] += __shfl_down(s1[zt], 16, 64);
    s1[zt] += __shfl_down(s1[zt], 32, 64);
    s2[zt] += __shfl_down(s2[zt], 16, 64);
    s2[zt] += __shfl_down(s2[zt], 32, 64);
  }
  if (l < 16) {
#pragma unroll
    for (int zt = 0; zt < 4; ++zt) {
      sp1[w * 64 + zt * 16 + m] = s1[zt];
      sp2[w * 64 + zt * 16 + m] = s2[zt];
    }
  }
  __syncthreads();
  if (t < 64) {
    float a1 = 0.f, a2 = 0.f;
#pragma unroll
    for (int k = 0; k < 8; ++k) {
      a1 += sp1[k * 64 + t];
      a2 += sp2[k * 64 + t];
    }
    part[(size_t)blockIdx.x * 128 + t] = a1;
    part[(size_t)blockIdx.x * 128 + 64 + t] = a2;
  }
}

// K4: block 0 = BN stats (4-way sliced); blocks 1..64 = pack ew2 f32 -> bf16
// (16 rows of 64 each) into ew2b [1024][32] u32 for the fused k_msg GEMM.
__global__ __launch_bounds__(256) void k_bnstat(const float* __restrict__ part,
    const float* __restrict__ bng, const float* __restrict__ bnb,
    const float* __restrict__ ew2,
    float* __restrict__ stat, unsigned* __restrict__ ew2b) {
  if (blockIdx.x == 0) {
    __shared__ float red[512];
    const int t = threadIdx.x;        // 256
    const int c = t & 63, q = t >> 6; // q 0..3
    float s1 = 0.f, s2 = 0.f;
#pragma unroll 4
    for (int b = q; b < 256; b += 4) {
      s1 += part[(size_t)b * 128 + c];
      s2 += part[(size_t)b * 128 + 64 + c];
    }
    red[q * 64 + c] = s1;
    red[256 + q * 64 + c] = s2;
    __syncthreads();
    if (t < 64) {
      float a1 = red[t] + red[64 + t] + red[128 + t] + red[192 + t];
      float a2 = red[256 + t] + red[320 + t] + red[384 + t] + red[448 + t];
      float mean = a1 * (1.f / NROW);
      float var = a2 * (1.f / NROW) - mean * mean;
      float rstd = rsqrtf(var + 1e-5f);
      float sc = bng[t] * rstd;
      stat[t] = sc;
      stat[64 + t] = bnb[t] - mean * sc;
    }
  } else {
    const int rb = blockIdx.x - 1;    // 0..63 -> rows rb*16 .. rb*16+15
    const int t = threadIdx.x;
#pragma unroll
    for (int it = 0; it < 2; ++it) {
      int id2 = t + 256 * it;          // 0..511 col-pairs
      int r = rb * 16 + (id2 >> 5);    // row
      int cp = id2 & 31;               // col-pair 0..31
      float2 v = *(const float2*)(ew2 + (size_t)r * 64 + 2 * cp);
      ew2b[(size_t)r * 32 + cp] = pkbf(v.x, v.y);
    }
  }
}

// K7 (fused, v2): one block per b, 512 threads / 8 waves. Latent GEMM in-block
// into LDS latB (9-u32 rows), logits+softmax, msg main loop 8 iters/wave.
// LDS 80256 B -> 2 blocks/CU (16 waves/CU). QKL overlays MT (lifetimes disjoint).
constexpr int LATB_OFF = 0;        // [1024][18] bf16, 36B rows (r = i*32+j)
constexpr int H3B_OFF  = 36864;    // [32][72] bf16, 144B rows
constexpr int W1H_OFF  = 41472;    // [64][72] bf16
constexpr int W1L_OFF  = 50688;    // [64][20] bf16
constexpr int W2P_OFF  = 53248;    // [16][72] bf16 (pi-permuted c)
constexpr int ALL_OFF  = 55552;    // [32][33] f32 alpha
constexpr int MT_OFF   = 59776;    // 8 waves x 2560B private transpose buf; xz+QKL overlays pre-main-loop
constexpr int QKL_OFF  = MT_OFF + 4608;   // [32][20] f32 qk (overlay; dead before wb writes)
__global__ __launch_bounds__(512, 1) void k_msg(
    const unsigned* __restrict__ ew2b, const float* __restrict__ stat,
    const float* __restrict__ z1T, const float* __restrict__ eb2,
    const float* __restrict__ eps,
    const float* __restrict__ qkT,
    const float* __restrict__ qT, const float* __restrict__ hrow,
    const float* __restrict__ w1, const float* __restrict__ b1,
    const float* __restrict__ w2, const float* __restrict__ b2,
    float* __restrict__ out) {
  __shared__ char smem[80256];
  const int t = threadIdx.x;
  const int b = blockIdx.x;
  const int b32 = b * 32;
  unsigned* latB_dw = (unsigned*)(smem + LATB_OFF);

  const int w = t >> 6, l = t & 63;
  const int m = l & 15, g = l >> 4;

  // ---- staging (512 threads) ----
  {  // xz: z1 slice [32 rows][64 k] -> BN+lrelu -> bf16 @ MT_OFF overlay
    short* xz = (short*)(smem + MT_OFF);
    float zv[4];
#pragma unroll
    for (int it = 0; it < 4; ++it) {
      int idx = t + 512 * it;          // 0..2047
      int i = idx & 31, c = idx >> 5;  // row 0..31, col 0..63
      zv[it] = z1T[(size_t)c * NROW + b32 + i];
    }
#pragma unroll
    for (int it = 0; it < 4; ++it) {
      int idx = t + 512 * it;
      int i = idx & 31, c = idx >> 5;
      float v = lrelu_(fmaf(stat[c], zv[it], stat[64 + c]));
      xz[i * 72 + c] = (short)((__float_as_uint(v) + 0x8000u) >> 16);
    }
  }
  {  // qkL[i][l] from qkT (512 entries = 1/thread)
    float* qkL = (float*)(smem + QKL_OFF);
    int i = t & 31, ll = t >> 5;       // ll 0..15
    qkL[i * 20 + ll] = qkT[(size_t)ll * NROW + b32 + i];
  }
  {  // h3B[j][k] bf16 from row-major h
    int cp = t & 31, jbase = t >> 5;   // jbase 0..15
    const float2* h2 = (const float2*)hrow;
    float2 hv[2];
#pragma unroll
    for (int it = 0; it < 2; ++it)
      hv[it] = h2[((size_t)(b32 + jbase + 16 * it) * 64 + 2 * cp) >> 1];
    unsigned* dst = (unsigned*)(smem + H3B_OFF);
#pragma unroll
    for (int it = 0; it < 2; ++it)
      dst[(jbase + 16 * it) * 36 + cp] = pkbf(hv[it].x, hv[it].y);
  }
  {  // w1hL[c][k] (k<64)
    int kp = t & 31, cb = t >> 5;      // cb 0..15
    const float2* w12 = (const float2*)w1;
    float2 wv[4];
#pragma unroll
    for (int it = 0; it < 4; ++it)
      wv[it] = w12[((cb + 16 * it) * 80 + 2 * kp) >> 1];
    unsigned* dst = (unsigned*)(smem + W1H_OFF);
#pragma unroll
    for (int it = 0; it < 4; ++it)
      dst[(cb + 16 * it) * 36 + kp] = pkbf(wv[it].x, wv[it].y);
  }
  {  // w1latL[c][l] (512 entries = 1/thread)
    int lp = t & 7, cc = t >> 3;       // cc 0..63
    const float2* w12 = (const float2*)w1;
    float2 wv = w12[(cc * 80 + 64 + 2 * lp) >> 1];
    unsigned* dst = (unsigned*)(smem + W1L_OFF);
    dst[cc * 10 + lp] = pkbf(wv.x, wv.y);
  }
  {  // w2P[nn][p] = w2[nn][c(p)] (512 entries = 1/thread)
    int pp = t & 31, nn = t >> 5;      // nn 0..15
    const float2* w22 = (const float2*)w2;
    int p = 2 * pp;
    int c = ((p >> 2) & 3) * 16 + (p >> 4) * 4 + (p & 3);
    float2 wv0 = w22[(nn * 64 + c) >> 1];
    unsigned* dst = (unsigned*)(smem + W2P_OFF);
    dst[nn * 36 + pp] = pkbf(wv0.x, wv0.y);
  }
  __syncthreads();   // all staging (incl. xz, QKL) visible

  // ---- latent GEMM: lat[32][512] -> latB (LDS), wave w owns j-tiles w*4..w*4+3 ----
  {
    const short* xzS = (const short*)(smem + MT_OFF);
    bf16x8 afz[2][2];
#pragma unroll
    for (int mt = 0; mt < 2; ++mt)
#pragma unroll
      for (int ks = 0; ks < 2; ++ks)
        afz[mt][ks] = *(const bf16x8*)(xzS + (mt * 16 + m) * 72 + ks * 32 + g * 8);
    const uint4e* w4 = (const uint4e*)ew2b;
    const float stdfloor = 0.04472135955f;   // sqrt(0.002)
#pragma unroll 2
    for (int ci8 = 0; ci8 < 4; ++ci8) {
      int ci = w * 4 + ci8;                  // j-tile 0..31
      int c = ci * 16 + m;                   // latent column
      union { uint4e u; bf16x8 h; } bmu[2], blv[2];
#pragma unroll
      for (int ks = 0; ks < 2; ++ks) {
        bmu[ks].u = w4[(size_t)(ci * 16 + m) * 8 + ks * 4 + g];
        blv[ks].u = w4[(size_t)(512 + ci * 16 + m) * 8 + ks * 4 + g];
      }
      float ep[2][4];
#pragma unroll
      for (int mt = 0; mt < 2; ++mt)
#pragma unroll
        for (int reg = 0; reg < 4; ++reg)
          ep[mt][reg] = eps[(size_t)(b32 + mt * 16 + g * 4 + reg) * 512 + c];
      f32x4 accm[2], accl[2];
#pragma unroll
      for (int mt = 0; mt < 2; ++mt) {
        accm[mt] = (f32x4){0.f, 0.f, 0.f, 0.f};
        accl[mt] = (f32x4){0.f, 0.f, 0.f, 0.f};
      }
#pragma unroll
      for (int ks = 0; ks < 2; ++ks)
#pragma unroll
        for (int mt = 0; mt < 2; ++mt) {
          accm[mt] = __builtin_amdgcn_mfma_f32_16x16x32_bf16(afz[mt][ks], bmu[ks].h, accm[mt], 0, 0, 0);
          accl[mt] = __builtin_amdgcn_mfma_f32_16x16x32_bf16(afz[mt][ks], blv[ks].h, accl[mt], 0, 0, 0);
        }
      float ebm = eb2[c], ebl = eb2[DH + c];
#pragma unroll
      for (int mt = 0; mt < 2; ++mt)
#pragma unroll
        for (int reg = 0; reg < 4; ++reg) {
          float mu = accm[mt][reg] + ebm;
          float lv = accl[mt][reg] + ebl;
          float sd = fmaxf(__expf(0.5f * lv), stdfloor);
          float lat = fmaf(sd, ep[mt][reg], mu);
          float lat2 = __shfl_xor(lat, 1, 64);
          if (!(m & 1)) {
            int i = mt * 16 + g * 4 + reg;
            latB_dw[(i * 32 + ci) * 9 + (m >> 1)] = pkbf(lat, lat2);
          }
        }
    }
  }
  __syncthreads();   // latB complete before logits

  // ---- logits + softmax -> alL (reads latB + qkL) ----
  {
    const float* qkL = (const float*)(smem + QKL_OFF);
    float* alL = (float*)(smem + ALL_OFF);
#pragma unroll 1
    for (int p = 0; p < 2; ++p) {
      int i = (t >> 5) + 16 * p;
      int j = t & 31;
      const unsigned* lr = latB_dw + (i * 32 + j) * 9;
      float acc = 0.f;
#pragma unroll
      for (int d = 0; d < 8; ++d) {
        unsigned u = lr[d];
        float lo = __uint_as_float(u << 16);
        float hi = __uint_as_float(u & 0xffff0000u);
        acc = fmaf(lo, qkL[i * 20 + 2 * d], acc);
        acc = fmaf(hi, qkL[i * 20 + 2 * d + 1], acc);
      }
      if (j == i) acc = -1e9f;
      float mx = acc;
#pragma unroll
      for (int msk = 16; msk > 0; msk >>= 1) mx = fmaxf(mx, __shfl_xor(mx, msk, 32));
      float e = __expf(acc - mx);
      float s = e;
#pragma unroll
      for (int msk = 16; msk > 0; msk >>= 1) s += __shfl_xor(s, msk, 32);
      alL[i * 33 + j] = e / s;
    }
  }

  const int n15 = l & 15, q = l >> 4;
  const int jh = w & 1, ibase = (w >> 1) * 8;
  const bool kact = (q < 2);

  // ---- phase 1: hp[ct][reg] for (c = ct*16+q*4+reg, j = jh*16+n15) ----
  f32x4 hp[4];
#pragma unroll
  for (int ct = 0; ct < 4; ++ct) hp[ct] = (f32x4){0.f, 0.f, 0.f, 0.f};
#pragma unroll
  for (int ct = 0; ct < 4; ++ct)
#pragma unroll
    for (int ks = 0; ks < 2; ++ks) {
      bf16x8 aF = *(const bf16x8*)(smem + W1H_OFF + (ct * 16 + n15) * 144 + ks * 64 + q * 16);
      bf16x8 bF = *(const bf16x8*)(smem + H3B_OFF + (jh * 16 + n15) * 144 + ks * 64 + q * 16);
      hp[ct] = __builtin_amdgcn_mfma_f32_16x16x32_bf16(aF, bF, hp[ct], 0, 0, 0);
    }
#pragma unroll
  for (int ct = 0; ct < 4; ++ct)
#pragma unroll
    for (int reg = 0; reg < 4; ++reg)
      hp[ct][reg] += b1[ct * 16 + q * 4 + reg];

  // hoisted fragments
  bf16x8 aL[4];
#pragma unroll
  for (int ct = 0; ct < 4; ++ct) {
    union { unsigned u[4]; bf16x8 h; } tmp;
    tmp.u[0] = tmp.u[1] = tmp.u[2] = tmp.u[3] = 0u;
    if (kact) {
      const unsigned* p = (const unsigned*)(smem + W1L_OFF) + (ct * 16 + n15) * 10 + q * 4;
      uint2e d0 = *(const uint2e*)p;
      uint2e d1 = *(const uint2e*)(p + 2);
      tmp.u[0] = d0.x; tmp.u[1] = d0.y; tmp.u[2] = d1.x; tmp.u[3] = d1.y;
    }
    aL[ct] = tmp.h;
  }
  bf16x8 w2F[2];
#pragma unroll
  for (int ks = 0; ks < 2; ++ks)
    w2F[ks] = *(const bf16x8*)(smem + W2P_OFF + n15 * 144 + ks * 64 + q * 16);
  float b2v[4];
#pragma unroll
  for (int reg = 0; reg < 4; ++reg) b2v[reg] = b2[q * 4 + reg];

  __syncthreads();  // alL complete; xz+QKL dead from here (wb overlays them)

  // ---- main i loop (8 iterations/wave) ----
  float agg[4] = {0.f, 0.f, 0.f, 0.f};
  char* wb = smem + MT_OFF + w * 2560;
  const float* alLf = (const float*)(smem + ALL_OFF);
#pragma unroll 1
  for (int it = 0; it < 8; ++it) {
    int ii = ibase + it;
    int r = ii * 32 + jh * 16 + n15;
    union { unsigned u[4]; bf16x8 h; } latF;
    latF.u[0] = latF.u[1] = latF.u[2] = latF.u[3] = 0u;
    if (kact) {
      const unsigned* p = latB_dw + r * 9 + q * 4;
      latF.u[0] = p[0]; latF.u[1] = p[1]; latF.u[2] = p[2]; latF.u[3] = p[3];
    }
    f32x4 acc[4];
#pragma unroll
    for (int ct = 0; ct < 4; ++ct) {
      acc[ct] = (f32x4){0.f, 0.f, 0.f, 0.f};
      acc[ct] = __builtin_amdgcn_mfma_f32_16x16x32_bf16(aL[ct], latF.h, acc[ct], 0, 0, 0);
    }
    // lrelu + pack + pi-transpose write (per-wave private buffer, no barrier)
#pragma unroll
    for (int h = 0; h < 2; ++h) {
      float m0[4], m1[4];
#pragma unroll
      for (int reg = 0; reg < 4; ++reg) {
        float v0 = acc[2 * h][reg] + hp[2 * h][reg];
        float v1 = acc[2 * h + 1][reg] + hp[2 * h + 1][reg];
        m0[reg] = fmaxf(v0, 0.01f * v0);
        m1[reg] = fmaxf(v1, 0.01f * v1);
      }
      uint4e pk4;
      pk4.x = pkbf(m0[0], m0[1]); pk4.y = pkbf(m0[2], m0[3]);
      pk4.z = pkbf(m1[0], m1[1]); pk4.w = pkbf(m1[2], m1[3]);
      int qp = (2 * q + h) & 3;
      *(uint4e*)(wb + (q >> 1) * 1280 + n15 * 80 + qp * 16) = pk4;
    }
    // phase 3
    f32x4 msg = (f32x4){0.f, 0.f, 0.f, 0.f};
#pragma unroll
    for (int ks = 0; ks < 2; ++ks) {
      bf16x8 mF = *(const bf16x8*)(wb + ks * 1280 + n15 * 80 + q * 16);
      msg = __builtin_amdgcn_mfma_f32_16x16x32_bf16(w2F[ks], mF, msg, 0, 0, 0);
    }
    float aw = alLf[ii * 33 + jh * 16 + n15];
#pragma unroll
    for (int reg = 0; reg < 4; ++reg)
      agg[reg] = fmaf(aw, msg[reg] + b2v[reg], agg[reg]);
  }
  // park agg in own wave buffer
  {
    f32x4 av; av[0] = agg[0]; av[1] = agg[1]; av[2] = agg[2]; av[3] = agg[3];
    *(f32x4*)(wb + n15 * 80 + q * 16) = av;
  }
  __syncthreads();
  // combine 4 i-quarters (waves jh2, jh2+2, jh2+4, jh2+6) and add q head
  {
    int jg = t >> 4, nn = t & 15;
    int jh2 = jg >> 4, jl = jg & 15;
    float s = qT[(size_t)nn * NROW + b32 + jg];
#pragma unroll
    for (int k = 0; k < 4; ++k)
      s += *(const float*)(smem + MT_OFF + (jh2 + 2 * k) * 2560 + jl * 80 + nn * 4);
    out[(size_t)b * 512 + t] = s;
  }
}

}  // namespace

extern "C" void kernel_launch(void* const* d_in, const int* in_sizes, int n_in,
                              void* d_out, int out_size, void* d_ws, size_t ws_size,
                              hipStream_t stream) {
  (void)in_sizes; (void)n_in; (void)out_size; (void)ws_size;
  const float* inputs = (const float*)d_in[0];
  const float* hidden = (const float*)d_in[1];
  const float* eps    = (const float*)d_in[2];
  const float* fc1w   = (const float*)d_in[3];
  const float* fc1b   = (const float*)d_in[4];
  const float* wih    = (const float*)d_in[5];
  const float* whh    = (const float*)d_in[6];
  const float* bih    = (const float*)d_in[7];
  const float* bhh    = (const float*)d_in[8];
  const float* fc2w   = (const float*)d_in[9];
  const float* fc2b   = (const float*)d_in[10];
  const float* ew1    = (const float*)d_in[11];
  const float* eb1    = (const float*)d_in[12];
  const float* bng    = (const float*)d_in[13];
  const float* bnb    = (const float*)d_in[14];
  const float* ew2    = (const float*)d_in[15];
  const float* eb2    = (const float*)d_in[16];
  const float* w1     = (const float*)d_in[17];
  const float* b1     = (const float*)d_in[18];
  const float* w2     = (const float*)d_in[19];
  const float* b2     = (const float*)d_in[20];
  const float* wqw    = (const float*)d_in[21];
  const float* wkw    = (const float*)d_in[23];

  float* ws = (float*)d_ws;
  float* qT     = ws + 2097152;       // 524288
  float* qkT    = ws + 2621440;       // 524288
  float* z1T    = ws + 3670016;       // 2097152
  float* part   = ws + 5767168;       // 32768 used
  float* stat   = ws + 5832704;       // 128
  unsigned* ew2b = (unsigned*)(ws + 5832832);  // [1024][32] u32 (bf16-packed ew2)

  float* out_q = (float*)d_out;             // 32768 x 16
  float* out_h = (float*)d_out + 524288;    // 32768 x 64

  hipLaunchKernelGGL(k_fgru, dim3(256), dim3(512), 0, stream,
                     inputs, hidden, fc1w, fc1b, wih, whh, bih, bhh,
                     fc2w, fc2b, wqw, wkw, ew1, eb1,
                     qT, qkT, z1T, part, out_h);
  hipLaunchKernelGGL(k_bnstat, dim3(65), dim3(256), 0, stream, part, bng, bnb, ew2, stat, ew2b);
  hipLaunchKernelGGL(k_msg, dim3(1024), dim3(512), 0, stream,
                     ew2b, stat, z1T, eb2, eps, qkT, qT, out_h, w1, b1, w2, b2, out_q);
}